// Round 4
// baseline (636.349 us; speedup 1.0000x reference)
//
#include <hip/hip_runtime.h>
#include <math.h>

constexpr int EMBED = 1024;
constexpr int HEADS = 16;
constexpr int HDIM  = 64;
constexpr int BATCH = 2;
constexpr int SEQ   = 2048;
constexpr int MTOT  = BATCH * SEQ;   // 4096
constexpr int KSPL  = 3 * EMBED;     // 3072: K' for the 3-term split GEMM
constexpr int LDK   = 2 * EMBED;     // 2048: physical [hi|lo] row width

typedef unsigned short u16;
using bf16x8 = __attribute__((ext_vector_type(8))) short;
using f32x4  = __attribute__((ext_vector_type(4))) float;
using f32x16 = __attribute__((ext_vector_type(16))) float;
using u32x4  = __attribute__((ext_vector_type(4))) unsigned int;

__device__ __forceinline__ u16 f2bf(float f) {
    unsigned u = __builtin_bit_cast(unsigned, f);
    return (u16)((u + 0x7fffu + ((u >> 16) & 1u)) >> 16);
}
__device__ __forceinline__ float bf2f(u16 h) {
    unsigned u = ((unsigned)h) << 16;
    return __builtin_bit_cast(float, u);
}
__device__ __forceinline__ unsigned cvtpk(float lo, float hi) {
    unsigned r;
    asm("v_cvt_pk_bf16_f32 %0, %1, %2" : "=v"(r) : "v"(lo), "v"(hi));
    return r;
}

#define GLOAD16(gp, lp) __builtin_amdgcn_global_load_lds( \
    (const __attribute__((address_space(1))) unsigned int*)(gp), \
    (__attribute__((address_space(3))) unsigned int*)(lp), 16, 0, 0)

// ---------------------------------------------------------------------------
// Split f32 rows [rows][1024] into bf16 [rows][2048]: hi | lo.
// ---------------------------------------------------------------------------
__global__ __launch_bounds__(256)
void convert_split(const float* __restrict__ X, const float* __restrict__ Wq,
                   const float* __restrict__ Wp,
                   u16* __restrict__ Xs, u16* __restrict__ Wqs, u16* __restrict__ Wps)
{
    int m = blockIdx.x;                 // 0..8191
    int k = threadIdx.x * 4;
    const float* src; u16* dst;
    if (m < 4096)      { src = X  + (size_t)m * EMBED;          dst = Xs  + (size_t)m * LDK; }
    else if (m < 7168) { int lm = m - 4096; src = Wq + (size_t)lm * EMBED; dst = Wqs + (size_t)lm * LDK; }
    else               { int lm = m - 7168; src = Wp + (size_t)lm * EMBED; dst = Wps + (size_t)lm * LDK; }
    float4 v = *(const float4*)(src + k);
    ushort4 hi, lo;
    hi.x = f2bf(v.x); lo.x = f2bf(v.x - bf2f(hi.x));
    hi.y = f2bf(v.y); lo.y = f2bf(v.y - bf2f(hi.y));
    hi.z = f2bf(v.z); lo.z = f2bf(v.z - bf2f(hi.z));
    hi.w = f2bf(v.w); lo.w = f2bf(v.w - bf2f(hi.w));
    *(ushort4*)(dst + k)         = hi;
    *(ushort4*)(dst + EMBED + k) = lo;
}

// ---------------------------------------------------------------------------
// m97-structure bf16 MFMA mainloop, K'=3072 with per-segment source remap:
//   A segs: [hi | lo | hi], B segs: [hi | hi | lo]
// ---------------------------------------------------------------------------
__device__ __forceinline__ void mfma_loop(
    const u16* __restrict__ Ab, const u16* __restrict__ Bb,
    u16* As, u16* Bs, f32x4 (&acc)[4][4], int wid, int lane)
{
    const int wr = wid >> 1, wc = wid & 1;
    const int srow   = lane >> 2;
    const int schunk = (lane & 3) * 8;
    const int frow   = lane & 15;
    const int kg8    = (lane >> 4) * 8;

    for (int k0 = 0; k0 < KSPL; k0 += 32) {
        const int ka = k0 < 2048 ? k0 : k0 - 2048;
        const int kb = k0 < 1024 ? k0 : k0 - 1024;
        #pragma unroll
        for (int i = 0; i < 2; ++i) {
            const int rbase = wid * 32 + i * 16;
            GLOAD16(Ab + (size_t)(rbase + srow) * LDK + ka + schunk, &As[rbase * 32]);
            GLOAD16(Bb + (size_t)(rbase + srow) * LDK + kb + schunk, &Bs[rbase * 32]);
        }
        __syncthreads();
        bf16x8 a[4], b[4];
        #pragma unroll
        for (int mi = 0; mi < 4; ++mi)
            a[mi] = *(const bf16x8*)&As[(wr * 64 + mi * 16 + frow) * 32 + kg8];
        #pragma unroll
        for (int ni = 0; ni < 4; ++ni)
            b[ni] = *(const bf16x8*)&Bs[(wc * 64 + ni * 16 + frow) * 32 + kg8];
        #pragma unroll
        for (int mi = 0; mi < 4; ++mi)
            #pragma unroll
            for (int ni = 0; ni < 4; ++ni)
                acc[mi][ni] = __builtin_amdgcn_mfma_f32_16x16x32_bf16(
                    a[mi], b[ni], acc[mi][ni], 0, 0, 0);
        __syncthreads();
    }
}

__global__ __launch_bounds__(256)
void gemm_qkv_mfma(const u16* __restrict__ Xs, const u16* __restrict__ Wqs,
                   u16* __restrict__ Qhi, u16* __restrict__ Qlo,
                   u16* __restrict__ Khi, u16* __restrict__ Klo,
                   u16* __restrict__ Vt)
{
    __shared__ __align__(16) u16 As[128 * 32];
    __shared__ __align__(16) u16 Bs[128 * 32];
    const int bid = blockIdx.x;                       // 768
    const int swz = (bid & 7) * 96 + (bid >> 3);
    const int bm  = swz & 31;
    const int bn  = swz >> 5;
    const int wid = threadIdx.x >> 6, lane = threadIdx.x & 63;
    const int wr = wid >> 1, wc = wid & 1;

    f32x4 acc[4][4] = {};
    mfma_loop(Xs + (size_t)bm * 128 * LDK, Wqs + (size_t)bn * 128 * LDK,
              As, Bs, acc, wid, lane);

    const int b_ = bm >= 16;
    const int n0 = bm * 128 - b_ * SEQ + wr * 64 + ((lane >> 4) << 2);
    #pragma unroll
    for (int ni = 0; ni < 4; ++ni) {
        const int f   = bn * 128 + wc * 64 + ni * 16 + (lane & 15);
        const int h   = f / 192;
        const int rem = f - h * 192;
        const int d   = rem / 3;
        const int w   = rem - d * 3;
        const int bh  = b_ * HEADS + h;
        #pragma unroll
        for (int mi = 0; mi < 4; ++mi) {
            const int n_ = n0 + mi * 16;
            #pragma unroll
            for (int r = 0; r < 4; ++r) {
                float val = acc[mi][ni][r];
                u16 hi = f2bf(val);
                if (w == 2) {
                    Vt[((size_t)bh * HDIM + d) * SEQ + n_ + r] = hi;
                } else {
                    u16 lo = f2bf(val - bf2f(hi));
                    size_t idx = ((size_t)bh * SEQ + n_ + r) * HDIM + d;
                    if (w == 0) { Qhi[idx] = hi; Qlo[idx] = lo; }
                    else        { Khi[idx] = hi; Klo[idx] = lo; }
                }
            }
        }
    }
}

__global__ __launch_bounds__(256)
void gemm_proj_mfma(const u16* __restrict__ CTXs, const u16* __restrict__ Wps,
                    const float* __restrict__ bias, float* __restrict__ Out)
{
    __shared__ __align__(16) u16 As[128 * 32];
    __shared__ __align__(16) u16 Bs[128 * 32];
    const int bid = blockIdx.x;                       // 256
    const int swz = (bid & 7) * 32 + (bid >> 3);
    const int bm  = swz & 31;
    const int bn  = swz >> 5;
    const int wid = threadIdx.x >> 6, lane = threadIdx.x & 63;
    const int wr = wid >> 1, wc = wid & 1;

    f32x4 acc[4][4] = {};
    mfma_loop(CTXs + (size_t)bm * 128 * LDK, Wps + (size_t)bn * 128 * LDK,
              As, Bs, acc, wid, lane);

    const int m0 = bm * 128 + wr * 64 + ((lane >> 4) << 2);
    #pragma unroll
    for (int ni = 0; ni < 4; ++ni) {
        const int f  = bn * 128 + wc * 64 + ni * 16 + (lane & 15);
        const float bv = bias[f];
        #pragma unroll
        for (int mi = 0; mi < 4; ++mi) {
            const int m = m0 + mi * 16;
            #pragma unroll
            for (int r = 0; r < 4; ++r)
                Out[(size_t)(m + r) * EMBED + f] = fmaxf(acc[mi][ni][r] + bv, 0.f);
        }
    }
}

// ---------------------------------------------------------------------------
// Flash attention, split-K by 2.
// Block = 4 waves = 2 q-tiles (32 rows) x 2 k-halves (1024 each).
//  - S^T = K·Q^T, 3-term hi/lo split.
//  - In-register P->bf16 frag assembly: cvt_pk + v_permlane32_swap (T12).
//  - Defer-max rescale, THR=8 (T13).
//  - Pair merge through LDS, then transpose-store.
// ---------------------------------------------------------------------------
__global__ __launch_bounds__(256, 4)
void attn_mfma(const u16* __restrict__ Qhi, const u16* __restrict__ Qlo,
               const u16* __restrict__ Khi, const u16* __restrict__ Klo,
               const u16* __restrict__ Vt,  u16* __restrict__ CTXs)
{
    __shared__ __align__(16) float Lot[2][64][33];   // [qt][d][q] partner out
    __shared__ float Lml[2][2][32];                  // [qt][{m,l}][q]
    __shared__ __align__(16) float Ol[2][32][68];    // [qt][q][d] merged

    const int bid  = blockIdx.x;                     // 1024
    const int swz  = (bid & 7) * 128 + (bid >> 3);   // bijective XCD swizzle
    const int bh   = swz >> 5;                       // 0..31 (4 heads/XCD)
    const int qp   = swz & 31;                       // 64-row q group
    const int wid  = threadIdx.x >> 6;
    const int lane = threadIdx.x & 63;
    const int col  = lane & 31;
    const int g    = lane >> 5;
    const int qt   = wid >> 1;                       // q-tile within block
    const int kh   = wid & 1;                        // k-half

    const int q0   = qp * 64 + qt * 32;
    const int b_   = bh / HEADS;
    const int h    = bh % HEADS;
    const int kbeg = kh * (SEQ / 2);
    const int kend = kbeg + SEQ / 2;

    // Q fragments (B-operand of S^T)
    bf16x8 qh[4], ql[4];
    {
        const u16* qrh = Qhi + ((size_t)bh * SEQ + q0 + col) * HDIM + 8 * g;
        const u16* qrl = Qlo + ((size_t)bh * SEQ + q0 + col) * HDIM + 8 * g;
        #pragma unroll
        for (int dt = 0; dt < 4; ++dt) {
            qh[dt] = *(const bf16x8*)(qrh + 16 * dt);
            ql[dt] = *(const bf16x8*)(qrl + 16 * dt);
        }
    }

    const u16* kbh = Khi + (size_t)bh * SEQ * HDIM + 8 * g;
    const u16* kbl = Klo + (size_t)bh * SEQ * HDIM + 8 * g;
    const u16* vb  = Vt  + (size_t)bh * HDIM * SEQ + 8 * g;

    f32x16 ot0 = {}, ot1 = {};
    float m_run = -3.0e38f, l_run = 0.0f;

    bf16x8 kfh[4], kfl[4];
    #pragma unroll
    for (int dt = 0; dt < 4; ++dt) {
        kfh[dt] = *(const bf16x8*)(kbh + (size_t)(kbeg + col) * HDIM + 16 * dt);
        kfl[dt] = *(const bf16x8*)(kbl + (size_t)(kbeg + col) * HDIM + 16 * dt);
    }

    for (int k0 = kbeg; k0 < kend; k0 += 32) {
        // V frags (A-operand of PV)
        bf16x8 vf[2][2];
        #pragma unroll
        for (int dt = 0; dt < 2; ++dt)
            #pragma unroll
            for (int kt = 0; kt < 2; ++kt)
                vf[dt][kt] = *(const bf16x8*)(vb + (size_t)(dt * 32 + col) * SEQ + k0 + 16 * kt);

        bf16x8 nkh[4], nkl[4];
        const bool more = (k0 + 32) < kend;
        if (more) {
            #pragma unroll
            for (int dt = 0; dt < 4; ++dt) {
                nkh[dt] = *(const bf16x8*)(kbh + (size_t)(k0 + 32 + col) * HDIM + 16 * dt);
                nkl[dt] = *(const bf16x8*)(kbl + (size_t)(k0 + 32 + col) * HDIM + 16 * dt);
            }
        }

        // S^T = K · Q^T  (hi*hi + hi*lo + lo*hi)
        f32x16 st = {};
        #pragma unroll
        for (int dt = 0; dt < 4; ++dt) {
            st = __builtin_amdgcn_mfma_f32_32x32x16_bf16(kfh[dt], qh[dt], st, 0, 0, 0);
            st = __builtin_amdgcn_mfma_f32_32x32x16_bf16(kfh[dt], ql[dt], st, 0, 0, 0);
            st = __builtin_amdgcn_mfma_f32_32x32x16_bf16(kfl[dt], qh[dt], st, 0, 0, 0);
        }

        // ---- online softmax, defer-max (THR=8) ----
        float mx;
        {
            float m0 = fmaxf(fmaxf(st[0], st[1]),  fmaxf(st[2], st[3]));
            float m1 = fmaxf(fmaxf(st[4], st[5]),  fmaxf(st[6], st[7]));
            float m2 = fmaxf(fmaxf(st[8], st[9]),  fmaxf(st[10], st[11]));
            float m3 = fmaxf(fmaxf(st[12], st[13]), fmaxf(st[14], st[15]));
            mx = fmaxf(fmaxf(m0, m1), fmaxf(m2, m3));
        }
        mx = fmaxf(mx, __shfl_xor(mx, 32));
        if (__ballot(mx > m_run + 8.0f)) {
            float m_new = fmaxf(m_run, mx);
            float corr  = __expf(m_run - m_new);
            l_run *= corr;
            ot0 = ot0 * corr;
            ot1 = ot1 * corr;
            m_run = m_new;
        }

        float p[16];
        #pragma unroll
        for (int r = 0; r < 16; ++r) p[r] = __expf(st[r] - m_run);
        {
            float s0 = (p[0] + p[1]) + (p[2] + p[3]);
            float s1 = (p[4] + p[5]) + (p[6] + p[7]);
            float s2 = (p[8] + p[9]) + (p[10] + p[11]);
            float s3 = (p[12] + p[13]) + (p[14] + p[15]);
            float ps = (s0 + s1) + (s2 + s3);
            ps += __shfl_xor(ps, 32);
            l_run += ps;
        }

        // ---- P -> bf16 PV fragments in-register (cvt_pk + permlane32_swap) ----
        unsigned W0 = cvtpk(p[0],  p[1]),  W1 = cvtpk(p[2],  p[3]);
        unsigned W2 = cvtpk(p[4],  p[5]),  W3 = cvtpk(p[6],  p[7]);
        unsigned W4 = cvtpk(p[8],  p[9]),  W5 = cvtpk(p[10], p[11]);
        unsigned W6 = cvtpk(p[12], p[13]), W7 = cvtpk(p[14], p[15]);
        asm("v_permlane32_swap_b32 %0, %1" : "+v"(W0), "+v"(W2));
        asm("v_permlane32_swap_b32 %0, %1" : "+v"(W1), "+v"(W3));
        asm("v_permlane32_swap_b32 %0, %1" : "+v"(W4), "+v"(W6));
        asm("v_permlane32_swap_b32 %0, %1" : "+v"(W5), "+v"(W7));
        u32x4 t0 = {W0, W1, W2, W3};
        u32x4 t1 = {W4, W5, W6, W7};
        bf16x8 pf0 = __builtin_bit_cast(bf16x8, t0);
        bf16x8 pf1 = __builtin_bit_cast(bf16x8, t1);

        // ---- PV: out^T += V^T · P^T ----
        ot0 = __builtin_amdgcn_mfma_f32_32x32x16_bf16(vf[0][0], pf0, ot0, 0, 0, 0);
        ot1 = __builtin_amdgcn_mfma_f32_32x32x16_bf16(vf[1][0], pf0, ot1, 0, 0, 0);
        ot0 = __builtin_amdgcn_mfma_f32_32x32x16_bf16(vf[0][1], pf1, ot0, 0, 0, 0);
        ot1 = __builtin_amdgcn_mfma_f32_32x32x16_bf16(vf[1][1], pf1, ot1, 0, 0, 0);

        if (more) {
            #pragma unroll
            for (int dt = 0; dt < 4; ++dt) { kfh[dt] = nkh[dt]; kfl[dt] = nkl[dt]; }
        }
    }

    // ---- split-K merge + epilogue ----
    if (kh == 1) {
        #pragma unroll
        for (int r = 0; r < 16; ++r) {
            int d = (r & 3) + 8 * (r >> 2) + 4 * g;
            Lot[qt][d][col]      = ot0[r];
            Lot[qt][d + 32][col] = ot1[r];
        }
        if (g == 0) { Lml[qt][0][col] = m_run; Lml[qt][1][col] = l_run; }
    }
    __syncthreads();
    if (kh == 0) {
        float m1 = Lml[qt][0][col], l1 = Lml[qt][1][col];
        float m  = fmaxf(m_run, m1);
        float c0 = __expf(m_run - m), c1 = __expf(m1 - m);
        float l  = l_run * c0 + l1 * c1;
        float sc0 = c0 / (l * 32.0f);
        float sc1 = c1 / (l * 32.0f);
        #pragma unroll
        for (int r = 0; r < 16; ++r) {
            int d = (r & 3) + 8 * (r >> 2) + 4 * g;
            Ol[qt][col][d]      = ot0[r] * sc0 + Lot[qt][d][col] * sc1;
            Ol[qt][col][d + 32] = ot1[r] * sc0 + Lot[qt][d + 32][col] * sc1;
        }
        #pragma unroll
        for (int pass = 0; pass < 8; ++pass) {
            int qq = pass * 4 + (lane >> 4);
            int dd = (lane & 15) * 4;
            float4 t = *(const float4*)&Ol[qt][qq][dd];
            int m_ = b_ * SEQ + q0 + qq;
            ushort4 hv, lv;
            hv.x = f2bf(t.x); lv.x = f2bf(t.x - bf2f(hv.x));
            hv.y = f2bf(t.y); lv.y = f2bf(t.y - bf2f(hv.y));
            hv.z = f2bf(t.z); lv.z = f2bf(t.z - bf2f(hv.z));
            hv.w = f2bf(t.w); lv.w = f2bf(t.w - bf2f(hv.w));
            *(ushort4*)&CTXs[(size_t)m_ * LDK + h * HDIM + dd]         = hv;
            *(ushort4*)&CTXs[(size_t)m_ * LDK + EMBED + h * HDIM + dd] = lv;
        }
    }
}

extern "C" void kernel_launch(void* const* d_in, const int* in_sizes, int n_in,
                              void* d_out, int out_size, void* d_ws, size_t ws_size,
                              hipStream_t stream)
{
    const float* x      = (const float*)d_in[0];
    const float* w_qkv  = (const float*)d_in[1];
    const float* w_proj = (const float*)d_in[2];
    const float* b_proj = (const float*)d_in[3];
    float* out = (float*)d_out;

    const size_t seg = (size_t)BATCH * HEADS * SEQ * HDIM;   // 4 Mi elems
    char* w = (char*)d_ws;
    u16* Xs   = (u16*)w;  w += (size_t)MTOT * LDK * 2;       // 16 MiB
    u16* Wqs  = (u16*)w;  w += (size_t)3 * EMBED * LDK * 2;  // 12 MiB
    u16* Wps  = (u16*)w;  w += (size_t)EMBED * LDK * 2;      // 4 MiB
    u16* Qhi  = (u16*)w;  w += seg * 2;
    u16* Qlo  = (u16*)w;  w += seg * 2;
    u16* Khi  = (u16*)w;  w += seg * 2;
    u16* Klo  = (u16*)w;  w += seg * 2;
    u16* Vt   = (u16*)w;  w += seg * 2;
    u16* CTXs = Xs;   // Xs dead after gemm_qkv_mfma

    convert_split<<<dim3(8192), 256, 0, stream>>>(x, w_qkv, w_proj, Xs, Wqs, Wps);
    gemm_qkv_mfma<<<dim3(768), 256, 0, stream>>>(Xs, Wqs, Qhi, Qlo, Khi, Klo, Vt);
    attn_mfma<<<dim3(1024), 256, 0, stream>>>(Qhi, Qlo, Khi, Klo, Vt, CTXs);
    gemm_proj_mfma<<<dim3(256), 256, 0, stream>>>(CTXs, Wps, b_proj, out);
}

// Round 5
// 357.394 us; speedup vs baseline: 1.7805x; 1.7805x over previous
//
#include <hip/hip_runtime.h>
#include <math.h>

constexpr int EMBED = 1024;
constexpr int HEADS = 16;
constexpr int HDIM  = 64;
constexpr int BATCH = 2;
constexpr int SEQ   = 2048;
constexpr int MTOT  = BATCH * SEQ;   // 4096
constexpr int KSPL  = 3 * EMBED;     // 3072: K' for the 3-term split GEMM
constexpr int LDK   = 2 * EMBED;     // 2048: physical [hi|lo] row width

typedef unsigned short u16;
using bf16x8 = __attribute__((ext_vector_type(8))) short;
using f32x4  = __attribute__((ext_vector_type(4))) float;
using f32x16 = __attribute__((ext_vector_type(16))) float;
using u32x4  = __attribute__((ext_vector_type(4))) unsigned int;

__device__ __forceinline__ u16 f2bf(float f) {
    unsigned u = __builtin_bit_cast(unsigned, f);
    return (u16)((u + 0x7fffu + ((u >> 16) & 1u)) >> 16);
}
__device__ __forceinline__ float bf2f(u16 h) {
    unsigned u = ((unsigned)h) << 16;
    return __builtin_bit_cast(float, u);
}
__device__ __forceinline__ unsigned cvtpk(float lo, float hi) {
    unsigned r;
    asm("v_cvt_pk_bf16_f32 %0, %1, %2" : "=v"(r) : "v"(lo), "v"(hi));
    return r;
}

#define GLOAD16(gp, lp) __builtin_amdgcn_global_load_lds( \
    (const __attribute__((address_space(1))) unsigned int*)(gp), \
    (__attribute__((address_space(3))) unsigned int*)(lp), 16, 0, 0)

// ---------------------------------------------------------------------------
// Split f32 rows [rows][1024] into bf16 [rows][2048]: hi | lo.
// ---------------------------------------------------------------------------
__global__ __launch_bounds__(256)
void convert_split(const float* __restrict__ X, const float* __restrict__ Wq,
                   const float* __restrict__ Wp,
                   u16* __restrict__ Xs, u16* __restrict__ Wqs, u16* __restrict__ Wps)
{
    int m = blockIdx.x;                 // 0..8191
    int k = threadIdx.x * 4;
    const float* src; u16* dst;
    if (m < 4096)      { src = X  + (size_t)m * EMBED;          dst = Xs  + (size_t)m * LDK; }
    else if (m < 7168) { int lm = m - 4096; src = Wq + (size_t)lm * EMBED; dst = Wqs + (size_t)lm * LDK; }
    else               { int lm = m - 7168; src = Wp + (size_t)lm * EMBED; dst = Wps + (size_t)lm * LDK; }
    float4 v = *(const float4*)(src + k);
    ushort4 hi, lo;
    hi.x = f2bf(v.x); lo.x = f2bf(v.x - bf2f(hi.x));
    hi.y = f2bf(v.y); lo.y = f2bf(v.y - bf2f(hi.y));
    hi.z = f2bf(v.z); lo.z = f2bf(v.z - bf2f(hi.z));
    hi.w = f2bf(v.w); lo.w = f2bf(v.w - bf2f(hi.w));
    *(ushort4*)(dst + k)         = hi;
    *(ushort4*)(dst + EMBED + k) = lo;
}

// ---------------------------------------------------------------------------
// m97-structure bf16 MFMA mainloop, K'=3072 with per-segment source remap:
//   A segs: [hi | lo | hi], B segs: [hi | hi | lo]
// ---------------------------------------------------------------------------
__device__ __forceinline__ void mfma_loop(
    const u16* __restrict__ Ab, const u16* __restrict__ Bb,
    u16* As, u16* Bs, f32x4 (&acc)[4][4], int wid, int lane)
{
    const int wr = wid >> 1, wc = wid & 1;
    const int srow   = lane >> 2;
    const int schunk = (lane & 3) * 8;
    const int frow   = lane & 15;
    const int kg8    = (lane >> 4) * 8;

    for (int k0 = 0; k0 < KSPL; k0 += 32) {
        const int ka = k0 < 2048 ? k0 : k0 - 2048;
        const int kb = k0 < 1024 ? k0 : k0 - 1024;
        #pragma unroll
        for (int i = 0; i < 2; ++i) {
            const int rbase = wid * 32 + i * 16;
            GLOAD16(Ab + (size_t)(rbase + srow) * LDK + ka + schunk, &As[rbase * 32]);
            GLOAD16(Bb + (size_t)(rbase + srow) * LDK + kb + schunk, &Bs[rbase * 32]);
        }
        __syncthreads();
        bf16x8 a[4], b[4];
        #pragma unroll
        for (int mi = 0; mi < 4; ++mi)
            a[mi] = *(const bf16x8*)&As[(wr * 64 + mi * 16 + frow) * 32 + kg8];
        #pragma unroll
        for (int ni = 0; ni < 4; ++ni)
            b[ni] = *(const bf16x8*)&Bs[(wc * 64 + ni * 16 + frow) * 32 + kg8];
        #pragma unroll
        for (int mi = 0; mi < 4; ++mi)
            #pragma unroll
            for (int ni = 0; ni < 4; ++ni)
                acc[mi][ni] = __builtin_amdgcn_mfma_f32_16x16x32_bf16(
                    a[mi], b[ni], acc[mi][ni], 0, 0, 0);
        __syncthreads();
    }
}

__global__ __launch_bounds__(256)
void gemm_qkv_mfma(const u16* __restrict__ Xs, const u16* __restrict__ Wqs,
                   u16* __restrict__ Qhi, u16* __restrict__ Qlo,
                   u16* __restrict__ Khi, u16* __restrict__ Klo,
                   u16* __restrict__ Vt)
{
    __shared__ __align__(16) u16 As[128 * 32];
    __shared__ __align__(16) u16 Bs[128 * 32];
    const int bid = blockIdx.x;                       // 768
    const int swz = (bid & 7) * 96 + (bid >> 3);
    const int bm  = swz & 31;
    const int bn  = swz >> 5;
    const int wid = threadIdx.x >> 6, lane = threadIdx.x & 63;
    const int wr = wid >> 1, wc = wid & 1;

    f32x4 acc[4][4] = {};
    mfma_loop(Xs + (size_t)bm * 128 * LDK, Wqs + (size_t)bn * 128 * LDK,
              As, Bs, acc, wid, lane);

    const int b_ = bm >= 16;
    const int n0 = bm * 128 - b_ * SEQ + wr * 64 + ((lane >> 4) << 2);
    #pragma unroll
    for (int ni = 0; ni < 4; ++ni) {
        const int f   = bn * 128 + wc * 64 + ni * 16 + (lane & 15);
        const int h   = f / 192;
        const int rem = f - h * 192;
        const int d   = rem / 3;
        const int w   = rem - d * 3;
        const int bh  = b_ * HEADS + h;
        #pragma unroll
        for (int mi = 0; mi < 4; ++mi) {
            const int n_ = n0 + mi * 16;
            #pragma unroll
            for (int r = 0; r < 4; ++r) {
                float val = acc[mi][ni][r];
                u16 hi = f2bf(val);
                if (w == 2) {
                    Vt[((size_t)bh * HDIM + d) * SEQ + n_ + r] = hi;
                } else {
                    u16 lo = f2bf(val - bf2f(hi));
                    size_t idx = ((size_t)bh * SEQ + n_ + r) * HDIM + d;
                    if (w == 0) { Qhi[idx] = hi; Qlo[idx] = lo; }
                    else        { Khi[idx] = hi; Klo[idx] = lo; }
                }
            }
        }
    }
}

__global__ __launch_bounds__(256)
void gemm_proj_mfma(const u16* __restrict__ CTXs, const u16* __restrict__ Wps,
                    const float* __restrict__ bias, float* __restrict__ Out)
{
    __shared__ __align__(16) u16 As[128 * 32];
    __shared__ __align__(16) u16 Bs[128 * 32];
    const int bid = blockIdx.x;                       // 256
    const int swz = (bid & 7) * 32 + (bid >> 3);
    const int bm  = swz & 31;
    const int bn  = swz >> 5;
    const int wid = threadIdx.x >> 6, lane = threadIdx.x & 63;
    const int wr = wid >> 1, wc = wid & 1;

    f32x4 acc[4][4] = {};
    mfma_loop(CTXs + (size_t)bm * 128 * LDK, Wps + (size_t)bn * 128 * LDK,
              As, Bs, acc, wid, lane);

    const int m0 = bm * 128 + wr * 64 + ((lane >> 4) << 2);
    #pragma unroll
    for (int ni = 0; ni < 4; ++ni) {
        const int f  = bn * 128 + wc * 64 + ni * 16 + (lane & 15);
        const float bv = bias[f];
        #pragma unroll
        for (int mi = 0; mi < 4; ++mi) {
            const int m = m0 + mi * 16;
            #pragma unroll
            for (int r = 0; r < 4; ++r)
                Out[(size_t)(m + r) * EMBED + f] = fmaxf(acc[mi][ni][r] + bv, 0.f);
        }
    }
}

// ---------------------------------------------------------------------------
// Flash attention, split-K by 2. NO occupancy clamp: ~100 VGPR lands in the
// 128-VGPR tier = 4 waves/SIMD without spilling (R4's (256,4) forced 64 VGPR
// -> scratch spill -> 695 MB writes).
// ---------------------------------------------------------------------------
__global__ __launch_bounds__(256)
void attn_mfma(const u16* __restrict__ Qhi, const u16* __restrict__ Qlo,
               const u16* __restrict__ Khi, const u16* __restrict__ Klo,
               const u16* __restrict__ Vt,  u16* __restrict__ CTXs)
{
    __shared__ __align__(16) float Lot[2][64][33];   // [qt][d][q] partner out
    __shared__ float Lml[2][2][32];                  // [qt][{m,l}][q]
    __shared__ __align__(16) float Ol[2][32][68];    // [qt][q][d] merged

    const int bid  = blockIdx.x;                     // 1024
    const int swz  = (bid & 7) * 128 + (bid >> 3);   // bijective XCD swizzle
    const int bh   = swz >> 5;                       // 0..31 (4 heads/XCD)
    const int qp   = swz & 31;                       // 64-row q group
    const int wid  = threadIdx.x >> 6;
    const int lane = threadIdx.x & 63;
    const int col  = lane & 31;
    const int g    = lane >> 5;
    const int qt   = wid >> 1;                       // q-tile within block
    const int kh   = wid & 1;                        // k-half

    const int q0   = qp * 64 + qt * 32;
    const int b_   = bh / HEADS;
    const int h    = bh % HEADS;
    const int kbeg = kh * (SEQ / 2);
    const int kend = kbeg + SEQ / 2;

    // Q fragments (B-operand of S^T)
    bf16x8 qh[4], ql[4];
    {
        const u16* qrh = Qhi + ((size_t)bh * SEQ + q0 + col) * HDIM + 8 * g;
        const u16* qrl = Qlo + ((size_t)bh * SEQ + q0 + col) * HDIM + 8 * g;
        #pragma unroll
        for (int dt = 0; dt < 4; ++dt) {
            qh[dt] = *(const bf16x8*)(qrh + 16 * dt);
            ql[dt] = *(const bf16x8*)(qrl + 16 * dt);
        }
    }

    const u16* kbh = Khi + (size_t)bh * SEQ * HDIM + 8 * g;
    const u16* kbl = Klo + (size_t)bh * SEQ * HDIM + 8 * g;
    const u16* vb  = Vt  + (size_t)bh * HDIM * SEQ + 8 * g;

    f32x16 ot0 = {}, ot1 = {};
    float m_run = -3.0e38f, l_run = 0.0f;

    bf16x8 kfh[4], kfl[4];
    #pragma unroll
    for (int dt = 0; dt < 4; ++dt) {
        kfh[dt] = *(const bf16x8*)(kbh + (size_t)(kbeg + col) * HDIM + 16 * dt);
        kfl[dt] = *(const bf16x8*)(kbl + (size_t)(kbeg + col) * HDIM + 16 * dt);
    }

    for (int k0 = kbeg; k0 < kend; k0 += 32) {
        // V frags (A-operand of PV)
        bf16x8 vf[2][2];
        #pragma unroll
        for (int dt = 0; dt < 2; ++dt)
            #pragma unroll
            for (int kt = 0; kt < 2; ++kt)
                vf[dt][kt] = *(const bf16x8*)(vb + (size_t)(dt * 32 + col) * SEQ + k0 + 16 * kt);

        bf16x8 nkh[4], nkl[4];
        const bool more = (k0 + 32) < kend;
        if (more) {
            #pragma unroll
            for (int dt = 0; dt < 4; ++dt) {
                nkh[dt] = *(const bf16x8*)(kbh + (size_t)(k0 + 32 + col) * HDIM + 16 * dt);
                nkl[dt] = *(const bf16x8*)(kbl + (size_t)(k0 + 32 + col) * HDIM + 16 * dt);
            }
        }

        // S^T = K · Q^T  (hi*hi + hi*lo + lo*hi)
        f32x16 st = {};
        #pragma unroll
        for (int dt = 0; dt < 4; ++dt) {
            st = __builtin_amdgcn_mfma_f32_32x32x16_bf16(kfh[dt], qh[dt], st, 0, 0, 0);
            st = __builtin_amdgcn_mfma_f32_32x32x16_bf16(kfh[dt], ql[dt], st, 0, 0, 0);
            st = __builtin_amdgcn_mfma_f32_32x32x16_bf16(kfl[dt], qh[dt], st, 0, 0, 0);
        }

        // ---- online softmax, defer-max (THR=8) ----
        float mx;
        {
            float m0 = fmaxf(fmaxf(st[0], st[1]),  fmaxf(st[2], st[3]));
            float m1 = fmaxf(fmaxf(st[4], st[5]),  fmaxf(st[6], st[7]));
            float m2 = fmaxf(fmaxf(st[8], st[9]),  fmaxf(st[10], st[11]));
            float m3 = fmaxf(fmaxf(st[12], st[13]), fmaxf(st[14], st[15]));
            mx = fmaxf(fmaxf(m0, m1), fmaxf(m2, m3));
        }
        mx = fmaxf(mx, __shfl_xor(mx, 32));
        if (__ballot(mx > m_run + 8.0f)) {
            float m_new = fmaxf(m_run, mx);
            float corr  = __expf(m_run - m_new);
            l_run *= corr;
            ot0 = ot0 * corr;
            ot1 = ot1 * corr;
            m_run = m_new;
        }

        float p[16];
        #pragma unroll
        for (int r = 0; r < 16; ++r) p[r] = __expf(st[r] - m_run);
        {
            float s0 = (p[0] + p[1]) + (p[2] + p[3]);
            float s1 = (p[4] + p[5]) + (p[6] + p[7]);
            float s2 = (p[8] + p[9]) + (p[10] + p[11]);
            float s3 = (p[12] + p[13]) + (p[14] + p[15]);
            float ps = (s0 + s1) + (s2 + s3);
            ps += __shfl_xor(ps, 32);
            l_run += ps;
        }

        // ---- P -> bf16 PV fragments in-register (cvt_pk + permlane32_swap) ----
        unsigned W0 = cvtpk(p[0],  p[1]),  W1 = cvtpk(p[2],  p[3]);
        unsigned W2 = cvtpk(p[4],  p[5]),  W3 = cvtpk(p[6],  p[7]);
        unsigned W4 = cvtpk(p[8],  p[9]),  W5 = cvtpk(p[10], p[11]);
        unsigned W6 = cvtpk(p[12], p[13]), W7 = cvtpk(p[14], p[15]);
        asm("v_permlane32_swap_b32 %0, %1" : "+v"(W0), "+v"(W2));
        asm("v_permlane32_swap_b32 %0, %1" : "+v"(W1), "+v"(W3));
        asm("v_permlane32_swap_b32 %0, %1" : "+v"(W4), "+v"(W6));
        asm("v_permlane32_swap_b32 %0, %1" : "+v"(W5), "+v"(W7));
        u32x4 t0 = {W0, W1, W2, W3};
        u32x4 t1 = {W4, W5, W6, W7};
        bf16x8 pf0 = __builtin_bit_cast(bf16x8, t0);
        bf16x8 pf1 = __builtin_bit_cast(bf16x8, t1);

        // ---- PV: out^T += V^T · P^T ----
        ot0 = __builtin_amdgcn_mfma_f32_32x32x16_bf16(vf[0][0], pf0, ot0, 0, 0, 0);
        ot1 = __builtin_amdgcn_mfma_f32_32x32x16_bf16(vf[1][0], pf0, ot1, 0, 0, 0);
        ot0 = __builtin_amdgcn_mfma_f32_32x32x16_bf16(vf[0][1], pf1, ot0, 0, 0, 0);
        ot1 = __builtin_amdgcn_mfma_f32_32x32x16_bf16(vf[1][1], pf1, ot1, 0, 0, 0);

        if (more) {
            #pragma unroll
            for (int dt = 0; dt < 4; ++dt) { kfh[dt] = nkh[dt]; kfl[dt] = nkl[dt]; }
        }
    }

    // ---- split-K merge + epilogue ----
    if (kh == 1) {
        #pragma unroll
        for (int r = 0; r < 16; ++r) {
            int d = (r & 3) + 8 * (r >> 2) + 4 * g;
            Lot[qt][d][col]      = ot0[r];
            Lot[qt][d + 32][col] = ot1[r];
        }
        if (g == 0) { Lml[qt][0][col] = m_run; Lml[qt][1][col] = l_run; }
    }
    __syncthreads();
    if (kh == 0) {
        float m1 = Lml[qt][0][col], l1 = Lml[qt][1][col];
        float m  = fmaxf(m_run, m1);
        float c0 = __expf(m_run - m), c1 = __expf(m1 - m);
        float l  = l_run * c0 + l1 * c1;
        float sc0 = c0 / (l * 32.0f);
        float sc1 = c1 / (l * 32.0f);
        #pragma unroll
        for (int r = 0; r < 16; ++r) {
            int d = (r & 3) + 8 * (r >> 2) + 4 * g;
            Ol[qt][col][d]      = ot0[r] * sc0 + Lot[qt][d][col] * sc1;
            Ol[qt][col][d + 32] = ot1[r] * sc0 + Lot[qt][d + 32][col] * sc1;
        }
        #pragma unroll
        for (int pass = 0; pass < 8; ++pass) {
            int qq = pass * 4 + (lane >> 4);
            int dd = (lane & 15) * 4;
            float4 t = *(const float4*)&Ol[qt][qq][dd];
            int m_ = b_ * SEQ + q0 + qq;
            ushort4 hv, lv;
            hv.x = f2bf(t.x); lv.x = f2bf(t.x - bf2f(hv.x));
            hv.y = f2bf(t.y); lv.y = f2bf(t.y - bf2f(hv.y));
            hv.z = f2bf(t.z); lv.z = f2bf(t.z - bf2f(hv.z));
            hv.w = f2bf(t.w); lv.w = f2bf(t.w - bf2f(hv.w));
            *(ushort4*)&CTXs[(size_t)m_ * LDK + h * HDIM + dd]         = hv;
            *(ushort4*)&CTXs[(size_t)m_ * LDK + EMBED + h * HDIM + dd] = lv;
        }
    }
}

extern "C" void kernel_launch(void* const* d_in, const int* in_sizes, int n_in,
                              void* d_out, int out_size, void* d_ws, size_t ws_size,
                              hipStream_t stream)
{
    const float* x      = (const float*)d_in[0];
    const float* w_qkv  = (const float*)d_in[1];
    const float* w_proj = (const float*)d_in[2];
    const float* b_proj = (const float*)d_in[3];
    float* out = (float*)d_out;

    const size_t seg = (size_t)BATCH * HEADS * SEQ * HDIM;   // 4 Mi elems
    char* w = (char*)d_ws;
    u16* Xs   = (u16*)w;  w += (size_t)MTOT * LDK * 2;       // 16 MiB
    u16* Wqs  = (u16*)w;  w += (size_t)3 * EMBED * LDK * 2;  // 12 MiB
    u16* Wps  = (u16*)w;  w += (size_t)EMBED * LDK * 2;      // 4 MiB
    u16* Qhi  = (u16*)w;  w += seg * 2;
    u16* Qlo  = (u16*)w;  w += seg * 2;
    u16* Khi  = (u16*)w;  w += seg * 2;
    u16* Klo  = (u16*)w;  w += seg * 2;
    u16* Vt   = (u16*)w;  w += seg * 2;
    u16* CTXs = Xs;   // Xs dead after gemm_qkv_mfma

    convert_split<<<dim3(8192), 256, 0, stream>>>(x, w_qkv, w_proj, Xs, Wqs, Wps);
    gemm_qkv_mfma<<<dim3(768), 256, 0, stream>>>(Xs, Wqs, Qhi, Qlo, Khi, Klo, Vt);
    attn_mfma<<<dim3(1024), 256, 0, stream>>>(Qhi, Qlo, Khi, Klo, Vt, CTXs);
    gemm_proj_mfma<<<dim3(256), 256, 0, stream>>>(CTXs, Wps, b_proj, out);
}

// Round 6
// 307.078 us; speedup vs baseline: 2.0723x; 1.1639x over previous
//
#include <hip/hip_runtime.h>
#include <math.h>

constexpr int EMBED = 1024;
constexpr int HEADS = 16;
constexpr int HDIM  = 64;
constexpr int BATCH = 2;
constexpr int SEQ   = 2048;
constexpr int MTOT  = BATCH * SEQ;   // 4096
constexpr int KSPL  = 3 * EMBED;     // 3072: K' for the 3-term split GEMM
constexpr int LDK   = 2 * EMBED;     // 2048: physical [hi|lo] row width
constexpr int BHSZ  = SEQ * HDIM;    // 131072 elems per (b,h) slice

typedef unsigned short u16;
using bf16x8 = __attribute__((ext_vector_type(8))) short;
using f32x4  = __attribute__((ext_vector_type(4))) float;
using f32x16 = __attribute__((ext_vector_type(16))) float;
using u32x4  = __attribute__((ext_vector_type(4))) unsigned int;

__device__ __forceinline__ u16 f2bf(float f) {
    unsigned u = __builtin_bit_cast(unsigned, f);
    return (u16)((u + 0x7fffu + ((u >> 16) & 1u)) >> 16);
}
__device__ __forceinline__ float bf2f(u16 h) {
    unsigned u = ((unsigned)h) << 16;
    return __builtin_bit_cast(float, u);
}
__device__ __forceinline__ unsigned cvtpk(float lo, float hi) {
    unsigned r;
    asm("v_cvt_pk_bf16_f32 %0, %1, %2" : "=v"(r) : "v"(lo), "v"(hi));
    return r;
}

// Packed fragment layouts (per (b,h) slice of BHSZ elems):
//  Q/K: [tile=n/32][dt=d/16][lane=((d>>3)&1)*32 + n%32][j=d&7]
//       -> attn lane l loads 16B at tile*2048 + dt*512 + l*8  (fully coalesced)
//  V:   [tile=n/32][dt=d/32][kt=(n>>4)&1][lane=((n>>3)&1)*32 + d%32][j=n&7]
__device__ __forceinline__ size_t qk_pk(int n, int d) {
    return ((size_t)((n >> 5) * 4 + (d >> 4)) * 64 +
            (((d >> 3) & 1) * 32 + (n & 31))) * 8 + (d & 7);
}

#define GLOAD16(gp, lp) __builtin_amdgcn_global_load_lds( \
    (const __attribute__((address_space(1))) unsigned int*)(gp), \
    (__attribute__((address_space(3))) unsigned int*)(lp), 16, 0, 0)

// ---------------------------------------------------------------------------
// Split f32 rows [rows][1024] into bf16 [rows][2048]: hi | lo.
// ---------------------------------------------------------------------------
__global__ __launch_bounds__(256)
void convert_split(const float* __restrict__ X, const float* __restrict__ Wq,
                   const float* __restrict__ Wp,
                   u16* __restrict__ Xs, u16* __restrict__ Wqs, u16* __restrict__ Wps)
{
    int m = blockIdx.x;                 // 0..8191
    int k = threadIdx.x * 4;
    const float* src; u16* dst;
    if (m < 4096)      { src = X  + (size_t)m * EMBED;          dst = Xs  + (size_t)m * LDK; }
    else if (m < 7168) { int lm = m - 4096; src = Wq + (size_t)lm * EMBED; dst = Wqs + (size_t)lm * LDK; }
    else               { int lm = m - 7168; src = Wp + (size_t)lm * EMBED; dst = Wps + (size_t)lm * LDK; }
    float4 v = *(const float4*)(src + k);
    ushort4 hi, lo;
    hi.x = f2bf(v.x); lo.x = f2bf(v.x - bf2f(hi.x));
    hi.y = f2bf(v.y); lo.y = f2bf(v.y - bf2f(hi.y));
    hi.z = f2bf(v.z); lo.z = f2bf(v.z - bf2f(hi.z));
    hi.w = f2bf(v.w); lo.w = f2bf(v.w - bf2f(hi.w));
    *(ushort4*)(dst + k)         = hi;
    *(ushort4*)(dst + EMBED + k) = lo;
}

// ---------------------------------------------------------------------------
// m97-structure bf16 MFMA mainloop, K'=3072 with per-segment source remap:
//   A segs: [hi | lo | hi], B segs: [hi | hi | lo]
// ---------------------------------------------------------------------------
__device__ __forceinline__ void mfma_loop(
    const u16* __restrict__ Ab, const u16* __restrict__ Bb,
    u16* As, u16* Bs, f32x4 (&acc)[4][4], int wid, int lane)
{
    const int wr = wid >> 1, wc = wid & 1;
    const int srow   = lane >> 2;
    const int schunk = (lane & 3) * 8;
    const int frow   = lane & 15;
    const int kg8    = (lane >> 4) * 8;

    for (int k0 = 0; k0 < KSPL; k0 += 32) {
        const int ka = k0 < 2048 ? k0 : k0 - 2048;
        const int kb = k0 < 1024 ? k0 : k0 - 1024;
        #pragma unroll
        for (int i = 0; i < 2; ++i) {
            const int rbase = wid * 32 + i * 16;
            GLOAD16(Ab + (size_t)(rbase + srow) * LDK + ka + schunk, &As[rbase * 32]);
            GLOAD16(Bb + (size_t)(rbase + srow) * LDK + kb + schunk, &Bs[rbase * 32]);
        }
        __syncthreads();
        bf16x8 a[4], b[4];
        #pragma unroll
        for (int mi = 0; mi < 4; ++mi)
            a[mi] = *(const bf16x8*)&As[(wr * 64 + mi * 16 + frow) * 32 + kg8];
        #pragma unroll
        for (int ni = 0; ni < 4; ++ni)
            b[ni] = *(const bf16x8*)&Bs[(wc * 64 + ni * 16 + frow) * 32 + kg8];
        #pragma unroll
        for (int mi = 0; mi < 4; ++mi)
            #pragma unroll
            for (int ni = 0; ni < 4; ++ni)
                acc[mi][ni] = __builtin_amdgcn_mfma_f32_16x16x32_bf16(
                    a[mi], b[ni], acc[mi][ni], 0, 0, 0);
        __syncthreads();
    }
}

__global__ __launch_bounds__(256)
void gemm_qkv_mfma(const u16* __restrict__ Xs, const u16* __restrict__ Wqs,
                   u16* __restrict__ Qhi, u16* __restrict__ Qlo,
                   u16* __restrict__ Khi, u16* __restrict__ Klo,
                   u16* __restrict__ Vt)
{
    __shared__ __align__(16) u16 As[128 * 32];
    __shared__ __align__(16) u16 Bs[128 * 32];
    const int bid = blockIdx.x;                       // 768
    const int swz = (bid & 7) * 96 + (bid >> 3);
    const int bm  = swz & 31;
    const int bn  = swz >> 5;
    const int wid = threadIdx.x >> 6, lane = threadIdx.x & 63;
    const int wr = wid >> 1, wc = wid & 1;

    f32x4 acc[4][4] = {};
    mfma_loop(Xs + (size_t)bm * 128 * LDK, Wqs + (size_t)bn * 128 * LDK,
              As, Bs, acc, wid, lane);

    const int b_ = bm >= 16;
    const int n0 = bm * 128 - b_ * SEQ + wr * 64 + ((lane >> 4) << 2);
    #pragma unroll
    for (int ni = 0; ni < 4; ++ni) {
        const int f   = bn * 128 + wc * 64 + ni * 16 + (lane & 15);
        const int h   = f / 192;
        const int rem = f - h * 192;
        const int d   = rem / 3;
        const int w   = rem - d * 3;
        const size_t bhb = (size_t)(b_ * HEADS + h) * BHSZ;
        #pragma unroll
        for (int mi = 0; mi < 4; ++mi) {
            const int n_ = n0 + mi * 16;              // n_&7 in {0,4}
            if (w == 2) {
                // V packed: ((tile*2 + d/32)*2 + kt)*64 + lane, j = n&7 (+r)
                size_t base = bhb +
                    ((((size_t)(n_ >> 5) * 2 + (d >> 5)) * 2 + ((n_ >> 4) & 1)) * 64 +
                     (((n_ >> 3) & 1) * 32 + (d & 31))) * 8 + (n_ & 7);
                ushort4 pv;
                pv.x = f2bf(acc[mi][ni][0]);
                pv.y = f2bf(acc[mi][ni][1]);
                pv.z = f2bf(acc[mi][ni][2]);
                pv.w = f2bf(acc[mi][ni][3]);
                *(ushort4*)&Vt[base] = pv;
            } else {
                #pragma unroll
                for (int r = 0; r < 4; ++r) {
                    const int n = n_ + r;
                    float val = acc[mi][ni][r];
                    u16 hi = f2bf(val);
                    u16 lo = f2bf(val - bf2f(hi));
                    size_t idx = bhb + qk_pk(n, d);
                    if (w == 0) { Qhi[idx] = hi; Qlo[idx] = lo; }
                    else        { Khi[idx] = hi; Klo[idx] = lo; }
                }
            }
        }
    }
}

__global__ __launch_bounds__(256)
void gemm_proj_mfma(const u16* __restrict__ CTXs, const u16* __restrict__ Wps,
                    const float* __restrict__ bias, float* __restrict__ Out)
{
    __shared__ __align__(16) u16 As[128 * 32];
    __shared__ __align__(16) u16 Bs[128 * 32];
    const int bid = blockIdx.x;                       // 256
    const int swz = (bid & 7) * 32 + (bid >> 3);
    const int bm  = swz & 31;
    const int bn  = swz >> 5;
    const int wid = threadIdx.x >> 6, lane = threadIdx.x & 63;
    const int wr = wid >> 1, wc = wid & 1;

    f32x4 acc[4][4] = {};
    mfma_loop(CTXs + (size_t)bm * 128 * LDK, Wps + (size_t)bn * 128 * LDK,
              As, Bs, acc, wid, lane);

    const int m0 = bm * 128 + wr * 64 + ((lane >> 4) << 2);
    #pragma unroll
    for (int ni = 0; ni < 4; ++ni) {
        const int f  = bn * 128 + wc * 64 + ni * 16 + (lane & 15);
        const float bv = bias[f];
        #pragma unroll
        for (int mi = 0; mi < 4; ++mi) {
            const int m = m0 + mi * 16;
            #pragma unroll
            for (int r = 0; r < 4; ++r)
                Out[(size_t)(m + r) * EMBED + f] = fmaxf(acc[mi][ni][r] + bv, 0.f);
        }
    }
}

// ---------------------------------------------------------------------------
// Flash attention, split-K by 2, packed-fragment global layout: every K/V/Q
// fragment load is base + lane*16B (fully coalesced; R5 was L2-BW-bound on
// 128B/4KB-stride gathers: ~49KB L2 traffic per iter per wave -> now ~12KB).
// ---------------------------------------------------------------------------
__global__ __launch_bounds__(256)
void attn_mfma(const u16* __restrict__ Qhi, const u16* __restrict__ Qlo,
               const u16* __restrict__ Khi, const u16* __restrict__ Klo,
               const u16* __restrict__ Vt,  u16* __restrict__ CTXs)
{
    __shared__ __align__(16) float Lot[2][64][33];   // [qt][d][q] partner out
    __shared__ float Lml[2][2][32];                  // [qt][{m,l}][q]
    __shared__ __align__(16) float Ol[2][32][68];    // [qt][q][d] merged

    const int bid  = blockIdx.x;                     // 1024
    const int swz  = (bid & 7) * 128 + (bid >> 3);   // bijective XCD swizzle
    const int bh   = swz >> 5;                       // 0..31 (4 heads/XCD)
    const int qp   = swz & 31;                       // 64-row q group
    const int wid  = threadIdx.x >> 6;
    const int lane = threadIdx.x & 63;
    const int col  = lane & 31;
    const int g    = lane >> 5;
    const int qt   = wid >> 1;                       // q-tile within block
    const int kh   = wid & 1;                        // k-half

    const int q0   = qp * 64 + qt * 32;
    const int b_   = bh / HEADS;
    const int h    = bh % HEADS;
    const int tbeg = kh * (SEQ / 2 / 32);            // tile index range
    const int tend = tbeg + SEQ / 2 / 32;

    const size_t bhb = (size_t)bh * BHSZ;
    const u16* kb_hi = Khi + bhb + (size_t)lane * 8;
    const u16* kb_lo = Klo + bhb + (size_t)lane * 8;
    const u16* vb    = Vt  + bhb + (size_t)lane * 8;

    // Q fragments (B-operand of S^T), packed: tile*2048 + dt*512 + lane*8
    bf16x8 qh[4], ql[4];
    {
        const u16* qbh = Qhi + bhb + (size_t)(q0 >> 5) * 2048 + (size_t)lane * 8;
        const u16* qbl = Qlo + bhb + (size_t)(q0 >> 5) * 2048 + (size_t)lane * 8;
        #pragma unroll
        for (int dt = 0; dt < 4; ++dt) {
            qh[dt] = *(const bf16x8*)(qbh + dt * 512);
            ql[dt] = *(const bf16x8*)(qbl + dt * 512);
        }
    }

    f32x16 ot0 = {}, ot1 = {};
    float m_run = -3.0e38f, l_run = 0.0f;

    bf16x8 kfh[4], kfl[4];
    #pragma unroll
    for (int dt = 0; dt < 4; ++dt) {
        kfh[dt] = *(const bf16x8*)(kb_hi + (size_t)tbeg * 2048 + dt * 512);
        kfl[dt] = *(const bf16x8*)(kb_lo + (size_t)tbeg * 2048 + dt * 512);
    }

    for (int t = tbeg; t < tend; ++t) {
        // V frags (A-operand of PV): tile*2048 + dt*1024 + kt*512 + lane*8
        bf16x8 vf[2][2];
        #pragma unroll
        for (int dt = 0; dt < 2; ++dt)
            #pragma unroll
            for (int kt = 0; kt < 2; ++kt)
                vf[dt][kt] = *(const bf16x8*)(vb + (size_t)t * 2048 + dt * 1024 + kt * 512);

        bf16x8 nkh[4], nkl[4];
        const bool more = (t + 1) < tend;
        if (more) {
            #pragma unroll
            for (int dt = 0; dt < 4; ++dt) {
                nkh[dt] = *(const bf16x8*)(kb_hi + (size_t)(t + 1) * 2048 + dt * 512);
                nkl[dt] = *(const bf16x8*)(kb_lo + (size_t)(t + 1) * 2048 + dt * 512);
            }
        }

        // S^T = K · Q^T  (hi*hi + hi*lo + lo*hi)
        f32x16 st = {};
        #pragma unroll
        for (int dt = 0; dt < 4; ++dt) {
            st = __builtin_amdgcn_mfma_f32_32x32x16_bf16(kfh[dt], qh[dt], st, 0, 0, 0);
            st = __builtin_amdgcn_mfma_f32_32x32x16_bf16(kfh[dt], ql[dt], st, 0, 0, 0);
            st = __builtin_amdgcn_mfma_f32_32x32x16_bf16(kfl[dt], qh[dt], st, 0, 0, 0);
        }

        // ---- online softmax, defer-max (THR=8) ----
        float mx;
        {
            float m0 = fmaxf(fmaxf(st[0], st[1]),  fmaxf(st[2], st[3]));
            float m1 = fmaxf(fmaxf(st[4], st[5]),  fmaxf(st[6], st[7]));
            float m2 = fmaxf(fmaxf(st[8], st[9]),  fmaxf(st[10], st[11]));
            float m3 = fmaxf(fmaxf(st[12], st[13]), fmaxf(st[14], st[15]));
            mx = fmaxf(fmaxf(m0, m1), fmaxf(m2, m3));
        }
        mx = fmaxf(mx, __shfl_xor(mx, 32));
        if (__ballot(mx > m_run + 8.0f)) {
            float m_new = fmaxf(m_run, mx);
            float corr  = __expf(m_run - m_new);
            l_run *= corr;
            ot0 = ot0 * corr;
            ot1 = ot1 * corr;
            m_run = m_new;
        }

        float p[16];
        #pragma unroll
        for (int r = 0; r < 16; ++r) p[r] = __expf(st[r] - m_run);
        {
            float s0 = (p[0] + p[1]) + (p[2] + p[3]);
            float s1 = (p[4] + p[5]) + (p[6] + p[7]);
            float s2 = (p[8] + p[9]) + (p[10] + p[11]);
            float s3 = (p[12] + p[13]) + (p[14] + p[15]);
            float ps = (s0 + s1) + (s2 + s3);
            ps += __shfl_xor(ps, 32);
            l_run += ps;
        }

        // ---- P -> bf16 PV fragments in-register (cvt_pk + permlane32_swap) ----
        unsigned W0 = cvtpk(p[0],  p[1]),  W1 = cvtpk(p[2],  p[3]);
        unsigned W2 = cvtpk(p[4],  p[5]),  W3 = cvtpk(p[6],  p[7]);
        unsigned W4 = cvtpk(p[8],  p[9]),  W5 = cvtpk(p[10], p[11]);
        unsigned W6 = cvtpk(p[12], p[13]), W7 = cvtpk(p[14], p[15]);
        asm("v_permlane32_swap_b32 %0, %1" : "+v"(W0), "+v"(W2));
        asm("v_permlane32_swap_b32 %0, %1" : "+v"(W1), "+v"(W3));
        asm("v_permlane32_swap_b32 %0, %1" : "+v"(W4), "+v"(W6));
        asm("v_permlane32_swap_b32 %0, %1" : "+v"(W5), "+v"(W7));
        u32x4 t0 = {W0, W1, W2, W3};
        u32x4 t1 = {W4, W5, W6, W7};
        bf16x8 pf0 = __builtin_bit_cast(bf16x8, t0);
        bf16x8 pf1 = __builtin_bit_cast(bf16x8, t1);

        // ---- PV: out^T += V^T · P^T ----
        ot0 = __builtin_amdgcn_mfma_f32_32x32x16_bf16(vf[0][0], pf0, ot0, 0, 0, 0);
        ot1 = __builtin_amdgcn_mfma_f32_32x32x16_bf16(vf[1][0], pf0, ot1, 0, 0, 0);
        ot0 = __builtin_amdgcn_mfma_f32_32x32x16_bf16(vf[0][1], pf1, ot0, 0, 0, 0);
        ot1 = __builtin_amdgcn_mfma_f32_32x32x16_bf16(vf[1][1], pf1, ot1, 0, 0, 0);

        if (more) {
            #pragma unroll
            for (int dt = 0; dt < 4; ++dt) { kfh[dt] = nkh[dt]; kfl[dt] = nkl[dt]; }
        }
    }

    // ---- split-K merge + epilogue ----
    if (kh == 1) {
        #pragma unroll
        for (int r = 0; r < 16; ++r) {
            int d = (r & 3) + 8 * (r >> 2) + 4 * g;
            Lot[qt][d][col]      = ot0[r];
            Lot[qt][d + 32][col] = ot1[r];
        }
        if (g == 0) { Lml[qt][0][col] = m_run; Lml[qt][1][col] = l_run; }
    }
    __syncthreads();
    if (kh == 0) {
        float m1 = Lml[qt][0][col], l1 = Lml[qt][1][col];
        float m  = fmaxf(m_run, m1);
        float c0 = __expf(m_run - m), c1 = __expf(m1 - m);
        float l  = l_run * c0 + l1 * c1;
        float sc0 = c0 / (l * 32.0f);
        float sc1 = c1 / (l * 32.0f);
        #pragma unroll
        for (int r = 0; r < 16; ++r) {
            int d = (r & 3) + 8 * (r >> 2) + 4 * g;
            Ol[qt][col][d]      = ot0[r] * sc0 + Lot[qt][d][col] * sc1;
            Ol[qt][col][d + 32] = ot1[r] * sc0 + Lot[qt][d + 32][col] * sc1;
        }
        #pragma unroll
        for (int pass = 0; pass < 8; ++pass) {
            int qq = pass * 4 + (lane >> 4);
            int dd = (lane & 15) * 4;
            float4 t = *(const float4*)&Ol[qt][qq][dd];
            int m_ = b_ * SEQ + q0 + qq;
            ushort4 hv, lv;
            hv.x = f2bf(t.x); lv.x = f2bf(t.x - bf2f(hv.x));
            hv.y = f2bf(t.y); lv.y = f2bf(t.y - bf2f(hv.y));
            hv.z = f2bf(t.z); lv.z = f2bf(t.z - bf2f(hv.z));
            hv.w = f2bf(t.w); lv.w = f2bf(t.w - bf2f(hv.w));
            *(ushort4*)&CTXs[(size_t)m_ * LDK + h * HDIM + dd]         = hv;
            *(ushort4*)&CTXs[(size_t)m_ * LDK + EMBED + h * HDIM + dd] = lv;
        }
    }
}

extern "C" void kernel_launch(void* const* d_in, const int* in_sizes, int n_in,
                              void* d_out, int out_size, void* d_ws, size_t ws_size,
                              hipStream_t stream)
{
    const float* x      = (const float*)d_in[0];
    const float* w_qkv  = (const float*)d_in[1];
    const float* w_proj = (const float*)d_in[2];
    const float* b_proj = (const float*)d_in[3];
    float* out = (float*)d_out;

    const size_t seg = (size_t)BATCH * HEADS * SEQ * HDIM;   // 4 Mi elems
    char* w = (char*)d_ws;
    u16* Xs   = (u16*)w;  w += (size_t)MTOT * LDK * 2;       // 16 MiB
    u16* Wqs  = (u16*)w;  w += (size_t)3 * EMBED * LDK * 2;  // 12 MiB
    u16* Wps  = (u16*)w;  w += (size_t)EMBED * LDK * 2;      // 4 MiB
    u16* Qhi  = (u16*)w;  w += seg * 2;
    u16* Qlo  = (u16*)w;  w += seg * 2;
    u16* Khi  = (u16*)w;  w += seg * 2;
    u16* Klo  = (u16*)w;  w += seg * 2;
    u16* Vt   = (u16*)w;  w += seg * 2;
    u16* CTXs = Xs;   // Xs dead after gemm_qkv_mfma

    convert_split<<<dim3(8192), 256, 0, stream>>>(x, w_qkv, w_proj, Xs, Wqs, Wps);
    gemm_qkv_mfma<<<dim3(768), 256, 0, stream>>>(Xs, Wqs, Qhi, Qlo, Khi, Klo, Vt);
    attn_mfma<<<dim3(1024), 256, 0, stream>>>(Qhi, Qlo, Khi, Klo, Vt, CTXs);
    gemm_proj_mfma<<<dim3(256), 256, 0, stream>>>(CTXs, Wps, b_proj, out);
}

// Round 7
// 284.818 us; speedup vs baseline: 2.2342x; 1.0782x over previous
//
#include <hip/hip_runtime.h>
#include <math.h>

constexpr int EMBED = 1024;
constexpr int HEADS = 16;
constexpr int HDIM  = 64;
constexpr int BATCH = 2;
constexpr int SEQ   = 2048;
constexpr int MTOT  = BATCH * SEQ;   // 4096
constexpr int KSPL  = 3 * EMBED;     // 3072: K' for the 3-term split GEMM
constexpr int LDK   = 2 * EMBED;     // 2048: physical [hi|lo] row width
constexpr int BHSZ  = SEQ * HDIM;    // 131072 elems per (b,h) slice

typedef unsigned short u16;
using bf16x8 = __attribute__((ext_vector_type(8))) short;
using f32x4  = __attribute__((ext_vector_type(4))) float;
using f32x16 = __attribute__((ext_vector_type(16))) float;
using u32x4  = __attribute__((ext_vector_type(4))) unsigned int;

__device__ __forceinline__ u16 f2bf(float f) {
    unsigned u = __builtin_bit_cast(unsigned, f);
    return (u16)((u + 0x7fffu + ((u >> 16) & 1u)) >> 16);
}
__device__ __forceinline__ float bf2f(u16 h) {
    unsigned u = ((unsigned)h) << 16;
    return __builtin_bit_cast(float, u);
}
__device__ __forceinline__ unsigned cvtpk(float lo, float hi) {
    unsigned r;
    asm("v_cvt_pk_bf16_f32 %0, %1, %2" : "=v"(r) : "v"(lo), "v"(hi));
    return r;
}

#define GLOAD16(gp, lp) __builtin_amdgcn_global_load_lds( \
    (const __attribute__((address_space(1))) unsigned int*)(gp), \
    (__attribute__((address_space(3))) unsigned int*)(lp), 16, 0, 0)

// Packed fragment layouts (per (b,h) slice of BHSZ elems):
//  Q/K: [tile=n/32][dt=d/16][lane=((d>>3)&1)*32 + n%32][j=d&7]
//  V:   [tile=n/32][dtv=d/32][kt=(n>>4)&1][lane=((n>>3)&1)*32 + d%32][j=n&7]

// ---------------------------------------------------------------------------
// Split f32 rows into bf16 [hi|lo]. w_qkv rows are PERMUTED on the fly:
// source f = h*192 + d*3 + which  ->  dest row which*1024 + h*64 + d,
// so each GEMM output block owns a single (which, head) pair.
// ---------------------------------------------------------------------------
__global__ __launch_bounds__(256)
void convert_split(const float* __restrict__ X, const float* __restrict__ Wq,
                   const float* __restrict__ Wp,
                   u16* __restrict__ Xs, u16* __restrict__ Wqs, u16* __restrict__ Wps)
{
    int m = blockIdx.x;                 // 0..8191
    int k = threadIdx.x * 4;
    const float* src; u16* dst;
    if (m < 4096) {
        src = X + (size_t)m * EMBED;          dst = Xs + (size_t)m * LDK;
    } else if (m < 7168) {
        int f = m - 4096;
        int h = f / 192, rem = f - h * 192, d = rem / 3, wq = rem - d * 3;
        int nrow = wq * 1024 + h * 64 + d;
        src = Wq + (size_t)f * EMBED;         dst = Wqs + (size_t)nrow * LDK;
    } else {
        int lm = m - 7168;
        src = Wp + (size_t)lm * EMBED;        dst = Wps + (size_t)lm * LDK;
    }
    float4 v = *(const float4*)(src + k);
    ushort4 hi, lo;
    hi.x = f2bf(v.x); lo.x = f2bf(v.x - bf2f(hi.x));
    hi.y = f2bf(v.y); lo.y = f2bf(v.y - bf2f(hi.y));
    hi.z = f2bf(v.z); lo.z = f2bf(v.z - bf2f(hi.z));
    hi.w = f2bf(v.w); lo.w = f2bf(v.w - bf2f(hi.w));
    *(ushort4*)(dst + k)         = hi;
    *(ushort4*)(dst + EMBED + k) = lo;
}

// ---------------------------------------------------------------------------
// bf16 MFMA mainloop, K'=3072 remapped (A: [hi|lo|hi], B: [hi|hi|lo]),
// now with depth-2 prefetch: 3 LDS buffers, counted vmcnt(4) (T3+T4 minimum),
// raw s_barrier + sched_barrier fencing (guide rules 18/21).
// ---------------------------------------------------------------------------
__device__ __forceinline__ void stage_pf(
    const u16* __restrict__ A, const u16* __restrict__ B,
    u16* As, u16* Bs, int buf, int t, int wid, int lane)
{
    const int k0 = t * 32;
    const int ka = k0 < 2048 ? k0 : k0 - 2048;
    const int kb = k0 < 1024 ? k0 : k0 - 1024;
    const int srow = lane >> 2, sc = (lane & 3) * 8;
    u16* ab = As + buf * 4096;
    u16* bb = Bs + buf * 4096;
    #pragma unroll
    for (int i = 0; i < 2; ++i) {
        const int rb = wid * 32 + i * 16;
        GLOAD16(A + (size_t)(rb + srow) * LDK + ka + sc, ab + rb * 32);
        GLOAD16(B + (size_t)(rb + srow) * LDK + kb + sc, bb + rb * 32);
    }
}

__device__ __forceinline__ void mfma_loop_pf(
    const u16* __restrict__ Ab, const u16* __restrict__ Bb,
    u16* As, u16* Bs, f32x4 (&acc)[4][4], int wid, int lane)
{
    constexpr int NT = KSPL / 32;   // 96
    const int wr = wid >> 1, wc = wid & 1;
    const int frow = lane & 15;
    const int kg8  = (lane >> 4) * 8;

    stage_pf(Ab, Bb, As, Bs, 0, 0, wid, lane);
    stage_pf(Ab, Bb, As, Bs, 1, 1, wid, lane);
    asm volatile("s_waitcnt vmcnt(4)" ::: "memory");
    __builtin_amdgcn_s_barrier();
    __builtin_amdgcn_sched_barrier(0);

    int cb = 0, sb = 2;
    for (int t = 0; t < NT; ++t) {
        if (t + 2 < NT) stage_pf(Ab, Bb, As, Bs, sb, t + 2, wid, lane);
        const u16* ap = As + cb * 4096;
        const u16* bp = Bs + cb * 4096;
        bf16x8 a[4], b[4];
        #pragma unroll
        for (int mi = 0; mi < 4; ++mi)
            a[mi] = *(const bf16x8*)&ap[(wr * 64 + mi * 16 + frow) * 32 + kg8];
        #pragma unroll
        for (int ni = 0; ni < 4; ++ni)
            b[ni] = *(const bf16x8*)&bp[(wc * 64 + ni * 16 + frow) * 32 + kg8];
        #pragma unroll
        for (int mi = 0; mi < 4; ++mi)
            #pragma unroll
            for (int ni = 0; ni < 4; ++ni)
                acc[mi][ni] = __builtin_amdgcn_mfma_f32_16x16x32_bf16(
                    a[mi], b[ni], acc[mi][ni], 0, 0, 0);
        // Pin all ds ops before the barrier, keep 4 loads (next-next tile)
        // in flight across it (counted vmcnt, T4).
        __builtin_amdgcn_sched_barrier(0);
        asm volatile("s_waitcnt lgkmcnt(0)" ::: "memory");
        if (t + 2 < NT) { asm volatile("s_waitcnt vmcnt(4)" ::: "memory"); }
        else            { asm volatile("s_waitcnt vmcnt(0)" ::: "memory"); }
        __builtin_amdgcn_s_barrier();
        __builtin_amdgcn_sched_barrier(0);
        cb = cb == 2 ? 0 : cb + 1;
        sb = sb == 2 ? 0 : sb + 1;
    }
}

// ---------------------------------------------------------------------------
// QKV GEMM. With permuted weights each wave owns one (which, head):
//   which = bn>>3, h = (bn&7)*2 + wc, d = ni*16 + (lane&15), 64 n-rows.
// Epilogue: wave-private 64x64 u16 LDS tile (reuses staging LDS, XOR-swizzled
// rows) -> fully coalesced 1KB packed-fragment stores.
// ---------------------------------------------------------------------------
__global__ __launch_bounds__(256)
void gemm_qkv_mfma(const u16* __restrict__ Xs, const u16* __restrict__ Wqs,
                   u16* __restrict__ Qhi, u16* __restrict__ Qlo,
                   u16* __restrict__ Khi, u16* __restrict__ Klo,
                   u16* __restrict__ Vt)
{
    __shared__ __align__(16) u16 SH[6 * 4096];   // 48 KB: As[3] | Bs[3]
    const int bid = blockIdx.x;                  // 768
    const int swz = (bid & 7) * 96 + (bid >> 3);
    const int bm  = swz & 31;
    const int bn  = swz >> 5;                    // 0..23
    const int wid = threadIdx.x >> 6, lane = threadIdx.x & 63;
    const int wr = wid >> 1, wc = wid & 1;

    f32x4 acc[4][4] = {};
    mfma_loop_pf(Xs + (size_t)bm * 128 * LDK, Wqs + (size_t)bn * 128 * LDK,
                 SH, SH + 3 * 4096, acc, wid, lane);
    // loop ends with s_barrier: all waves' staging reads retired -> LDS reusable

    const int which = bn >> 3;
    const int h     = ((bn & 7) << 1) | wc;
    const int b_    = bm >= 16;
    const size_t bhb = (size_t)(b_ * HEADS + h) * BHSZ;
    const int n0w = bm * 128 - b_ * SEQ + wr * 64;   // wave's 64-row n base
    char* T = (char*)(SH + wid * 4096);              // wave-private 8 KB

    if (which < 2) {
        u16* dstH = (which == 0 ? Qhi : Khi) + bhb;
        u16* dstL = (which == 0 ? Qlo : Klo) + bhb;
        #pragma unroll
        for (int pass = 0; pass < 2; ++pass) {
            u16* dst = pass ? dstL : dstH;
            #pragma unroll
            for (int mi = 0; mi < 4; ++mi)
                #pragma unroll
                for (int ni = 0; ni < 4; ++ni)
                    #pragma unroll
                    for (int r = 0; r < 4; ++r) {
                        float v = acc[mi][ni][r];
                        u16 hi = f2bf(v);
                        u16 ov = pass ? f2bf(v - bf2f(hi)) : hi;
                        int nl = ((lane >> 4) << 2) + mi * 16 + r;
                        int dl = ni * 16 + (lane & 15);
                        *(u16*)(T + nl * 128 + ((dl * 2) ^ ((nl & 7) << 4))) = ov;
                    }
            #pragma unroll
            for (int t2 = 0; t2 < 2; ++t2)
                #pragma unroll
                for (int dt = 0; dt < 4; ++dt) {
                    int nl   = t2 * 32 + (lane & 31);
                    int doff = (dt * 16 + (lane >> 5) * 8) * 2;
                    bf16x8 fr = *(const bf16x8*)(T + nl * 128 + (doff ^ ((nl & 7) << 4)));
                    int tile = (n0w >> 5) + t2;
                    *(bf16x8*)&dst[(size_t)(tile * 4 + dt) * 512 + lane * 8] = fr;
                }
        }
    } else {
        #pragma unroll
        for (int mi = 0; mi < 4; ++mi)
            #pragma unroll
            for (int ni = 0; ni < 4; ++ni)
                #pragma unroll
                for (int r = 0; r < 4; ++r) {
                    int nl = ((lane >> 4) << 2) + mi * 16 + r;
                    int dl = ni * 16 + (lane & 15);
                    *(u16*)(T + nl * 128 + ((dl * 2) ^ ((nl & 7) << 4))) =
                        f2bf(acc[mi][ni][r]);
                }
        u16* dst = Vt + bhb;
        #pragma unroll
        for (int t2 = 0; t2 < 2; ++t2)
            #pragma unroll
            for (int dtv = 0; dtv < 2; ++dtv)
                #pragma unroll
                for (int kt = 0; kt < 2; ++kt) {
                    int dcol = (dtv * 32 + (lane & 31)) * 2;
                    int nb   = t2 * 32 + kt * 16 + (lane >> 5) * 8;
                    bf16x8 fr;
                    #pragma unroll
                    for (int j = 0; j < 8; ++j) {
                        int nl = nb + j;
                        fr[j] = *(const short*)(T + nl * 128 + (dcol ^ ((nl & 7) << 4)));
                    }
                    int tile = (n0w >> 5) + t2;
                    *(bf16x8*)&dst[(size_t)(((tile * 2 + dtv) * 2 + kt) * 64 + lane) * 8] = fr;
                }
    }
}

__global__ __launch_bounds__(256)
void gemm_proj_mfma(const u16* __restrict__ CTXs, const u16* __restrict__ Wps,
                    const float* __restrict__ bias, float* __restrict__ Out)
{
    __shared__ __align__(16) u16 SH[6 * 4096];
    const int bid = blockIdx.x;                       // 256
    const int swz = (bid & 7) * 32 + (bid >> 3);
    const int bm  = swz & 31;
    const int bn  = swz >> 5;
    const int wid = threadIdx.x >> 6, lane = threadIdx.x & 63;
    const int wr = wid >> 1, wc = wid & 1;

    f32x4 acc[4][4] = {};
    mfma_loop_pf(CTXs + (size_t)bm * 128 * LDK, Wps + (size_t)bn * 128 * LDK,
                 SH, SH + 3 * 4096, acc, wid, lane);

    const int m0 = bm * 128 + wr * 64 + ((lane >> 4) << 2);
    #pragma unroll
    for (int ni = 0; ni < 4; ++ni) {
        const int f  = bn * 128 + wc * 64 + ni * 16 + (lane & 15);
        const float bv = bias[f];
        #pragma unroll
        for (int mi = 0; mi < 4; ++mi) {
            const int m = m0 + mi * 16;
            #pragma unroll
            for (int r = 0; r < 4; ++r)
                Out[(size_t)(m + r) * EMBED + f] = fmaxf(acc[mi][ni][r] + bv, 0.f);
        }
    }
}

// ---------------------------------------------------------------------------
// Flash attention (unchanged from R6): split-K by 2, packed-fragment loads,
// in-register P via cvt_pk+permlane32_swap, defer-max.
// ---------------------------------------------------------------------------
__global__ __launch_bounds__(256)
void attn_mfma(const u16* __restrict__ Qhi, const u16* __restrict__ Qlo,
               const u16* __restrict__ Khi, const u16* __restrict__ Klo,
               const u16* __restrict__ Vt,  u16* __restrict__ CTXs)
{
    __shared__ __align__(16) float Lot[2][64][33];
    __shared__ float Lml[2][2][32];
    __shared__ __align__(16) float Ol[2][32][68];

    const int bid  = blockIdx.x;                     // 1024
    const int swz  = (bid & 7) * 128 + (bid >> 3);
    const int bh   = swz >> 5;
    const int qp   = swz & 31;
    const int wid  = threadIdx.x >> 6;
    const int lane = threadIdx.x & 63;
    const int col  = lane & 31;
    const int g    = lane >> 5;
    const int qt   = wid >> 1;
    const int kh   = wid & 1;

    const int q0   = qp * 64 + qt * 32;
    const int b_   = bh / HEADS;
    const int h    = bh % HEADS;
    const int tbeg = kh * (SEQ / 2 / 32);
    const int tend = tbeg + SEQ / 2 / 32;

    const size_t bhb = (size_t)bh * BHSZ;
    const u16* kb_hi = Khi + bhb + (size_t)lane * 8;
    const u16* kb_lo = Klo + bhb + (size_t)lane * 8;
    const u16* vb    = Vt  + bhb + (size_t)lane * 8;

    bf16x8 qh[4], ql[4];
    {
        const u16* qbh = Qhi + bhb + (size_t)(q0 >> 5) * 2048 + (size_t)lane * 8;
        const u16* qbl = Qlo + bhb + (size_t)(q0 >> 5) * 2048 + (size_t)lane * 8;
        #pragma unroll
        for (int dt = 0; dt < 4; ++dt) {
            qh[dt] = *(const bf16x8*)(qbh + dt * 512);
            ql[dt] = *(const bf16x8*)(qbl + dt * 512);
        }
    }

    f32x16 ot0 = {}, ot1 = {};
    float m_run = -3.0e38f, l_run = 0.0f;

    bf16x8 kfh[4], kfl[4];
    #pragma unroll
    for (int dt = 0; dt < 4; ++dt) {
        kfh[dt] = *(const bf16x8*)(kb_hi + (size_t)tbeg * 2048 + dt * 512);
        kfl[dt] = *(const bf16x8*)(kb_lo + (size_t)tbeg * 2048 + dt * 512);
    }

    for (int t = tbeg; t < tend; ++t) {
        bf16x8 vf[2][2];
        #pragma unroll
        for (int dt = 0; dt < 2; ++dt)
            #pragma unroll
            for (int kt = 0; kt < 2; ++kt)
                vf[dt][kt] = *(const bf16x8*)(vb + (size_t)t * 2048 + dt * 1024 + kt * 512);

        bf16x8 nkh[4], nkl[4];
        const bool more = (t + 1) < tend;
        if (more) {
            #pragma unroll
            for (int dt = 0; dt < 4; ++dt) {
                nkh[dt] = *(const bf16x8*)(kb_hi + (size_t)(t + 1) * 2048 + dt * 512);
                nkl[dt] = *(const bf16x8*)(kb_lo + (size_t)(t + 1) * 2048 + dt * 512);
            }
        }

        f32x16 st = {};
        #pragma unroll
        for (int dt = 0; dt < 4; ++dt) {
            st = __builtin_amdgcn_mfma_f32_32x32x16_bf16(kfh[dt], qh[dt], st, 0, 0, 0);
            st = __builtin_amdgcn_mfma_f32_32x32x16_bf16(kfh[dt], ql[dt], st, 0, 0, 0);
            st = __builtin_amdgcn_mfma_f32_32x32x16_bf16(kfl[dt], qh[dt], st, 0, 0, 0);
        }

        float mx;
        {
            float m0 = fmaxf(fmaxf(st[0], st[1]),  fmaxf(st[2], st[3]));
            float m1 = fmaxf(fmaxf(st[4], st[5]),  fmaxf(st[6], st[7]));
            float m2 = fmaxf(fmaxf(st[8], st[9]),  fmaxf(st[10], st[11]));
            float m3 = fmaxf(fmaxf(st[12], st[13]), fmaxf(st[14], st[15]));
            mx = fmaxf(fmaxf(m0, m1), fmaxf(m2, m3));
        }
        mx = fmaxf(mx, __shfl_xor(mx, 32));
        if (__ballot(mx > m_run + 8.0f)) {
            float m_new = fmaxf(m_run, mx);
            float corr  = __expf(m_run - m_new);
            l_run *= corr;
            ot0 = ot0 * corr;
            ot1 = ot1 * corr;
            m_run = m_new;
        }

        float p[16];
        #pragma unroll
        for (int r = 0; r < 16; ++r) p[r] = __expf(st[r] - m_run);
        {
            float s0 = (p[0] + p[1]) + (p[2] + p[3]);
            float s1 = (p[4] + p[5]) + (p[6] + p[7]);
            float s2 = (p[8] + p[9]) + (p[10] + p[11]);
            float s3 = (p[12] + p[13]) + (p[14] + p[15]);
            float ps = (s0 + s1) + (s2 + s3);
            ps += __shfl_xor(ps, 32);
            l_run += ps;
        }

        unsigned W0 = cvtpk(p[0],  p[1]),  W1 = cvtpk(p[2],  p[3]);
        unsigned W2 = cvtpk(p[4],  p[5]),  W3 = cvtpk(p[6],  p[7]);
        unsigned W4 = cvtpk(p[8],  p[9]),  W5 = cvtpk(p[10], p[11]);
        unsigned W6 = cvtpk(p[12], p[13]), W7 = cvtpk(p[14], p[15]);
        asm("v_permlane32_swap_b32 %0, %1" : "+v"(W0), "+v"(W2));
        asm("v_permlane32_swap_b32 %0, %1" : "+v"(W1), "+v"(W3));
        asm("v_permlane32_swap_b32 %0, %1" : "+v"(W4), "+v"(W6));
        asm("v_permlane32_swap_b32 %0, %1" : "+v"(W5), "+v"(W7));
        u32x4 t0 = {W0, W1, W2, W3};
        u32x4 t1 = {W4, W5, W6, W7};
        bf16x8 pf0 = __builtin_bit_cast(bf16x8, t0);
        bf16x8 pf1 = __builtin_bit_cast(bf16x8, t1);

        ot0 = __builtin_amdgcn_mfma_f32_32x32x16_bf16(vf[0][0], pf0, ot0, 0, 0, 0);
        ot1 = __builtin_amdgcn_mfma_f32_32x32x16_bf16(vf[1][0], pf0, ot1, 0, 0, 0);
        ot0 = __builtin_amdgcn_mfma_f32_32x32x16_bf16(vf[0][1], pf1, ot0, 0, 0, 0);
        ot1 = __builtin_amdgcn_mfma_f32_32x32x16_bf16(vf[1][1], pf1, ot1, 0, 0, 0);

        if (more) {
            #pragma unroll
            for (int dt = 0; dt < 4; ++dt) { kfh[dt] = nkh[dt]; kfl[dt] = nkl[dt]; }
        }
    }

    if (kh == 1) {
        #pragma unroll
        for (int r = 0; r < 16; ++r) {
            int d = (r & 3) + 8 * (r >> 2) + 4 * g;
            Lot[qt][d][col]      = ot0[r];
            Lot[qt][d + 32][col] = ot1[r];
        }
        if (g == 0) { Lml[qt][0][col] = m_run; Lml[qt][1][col] = l_run; }
    }
    __syncthreads();
    if (kh == 0) {
        float m1 = Lml[qt][0][col], l1 = Lml[qt][1][col];
        float m  = fmaxf(m_run, m1);
        float c0 = __expf(m_run - m), c1 = __expf(m1 - m);
        float l  = l_run * c0 + l1 * c1;
        float sc0 = c0 / (l * 32.0f);
        float sc1 = c1 / (l * 32.0f);
        #pragma unroll
        for (int r = 0; r < 16; ++r) {
            int d = (r & 3) + 8 * (r >> 2) + 4 * g;
            Ol[qt][col][d]      = ot0[r] * sc0 + Lot[qt][d][col] * sc1;
            Ol[qt][col][d + 32] = ot1[r] * sc0 + Lot[qt][d + 32][col] * sc1;
        }
        #pragma unroll
        for (int pass = 0; pass < 8; ++pass) {
            int qq = pass * 4 + (lane >> 4);
            int dd = (lane & 15) * 4;
            float4 t = *(const float4*)&Ol[qt][qq][dd];
            int m_ = b_ * SEQ + q0 + qq;
            ushort4 hv, lv;
            hv.x = f2bf(t.x); lv.x = f2bf(t.x - bf2f(hv.x));
            hv.y = f2bf(t.y); lv.y = f2bf(t.y - bf2f(hv.y));
            hv.z = f2bf(t.z); lv.z = f2bf(t.z - bf2f(hv.z));
            hv.w = f2bf(t.w); lv.w = f2bf(t.w - bf2f(hv.w));
            *(ushort4*)&CTXs[(size_t)m_ * LDK + h * HDIM + dd]         = hv;
            *(ushort4*)&CTXs[(size_t)m_ * LDK + EMBED + h * HDIM + dd] = lv;
        }
    }
}

extern "C" void kernel_launch(void* const* d_in, const int* in_sizes, int n_in,
                              void* d_out, int out_size, void* d_ws, size_t ws_size,
                              hipStream_t stream)
{
    const float* x      = (const float*)d_in[0];
    const float* w_qkv  = (const float*)d_in[1];
    const float* w_proj = (const float*)d_in[2];
    const float* b_proj = (const float*)d_in[3];
    float* out = (float*)d_out;

    const size_t seg = (size_t)BATCH * HEADS * SEQ * HDIM;   // 4 Mi elems
    char* w = (char*)d_ws;
    u16* Xs   = (u16*)w;  w += (size_t)MTOT * LDK * 2;       // 16 MiB
    u16* Wqs  = (u16*)w;  w += (size_t)3 * EMBED * LDK * 2;  // 12 MiB
    u16* Wps  = (u16*)w;  w += (size_t)EMBED * LDK * 2;      // 4 MiB
    u16* Qhi  = (u16*)w;  w += seg * 2;
    u16* Qlo  = (u16*)w;  w += seg * 2;
    u16* Khi  = (u16*)w;  w += seg * 2;
    u16* Klo  = (u16*)w;  w += seg * 2;
    u16* Vt   = (u16*)w;  w += seg * 2;
    u16* CTXs = Xs;   // Xs dead after gemm_qkv_mfma

    convert_split<<<dim3(8192), 256, 0, stream>>>(x, w_qkv, w_proj, Xs, Wqs, Wps);
    gemm_qkv_mfma<<<dim3(768), 256, 0, stream>>>(Xs, Wqs, Qhi, Qlo, Khi, Klo, Vt);
    attn_mfma<<<dim3(1024), 256, 0, stream>>>(Qhi, Qlo, Khi, Klo, Vt, CTXs);
    gemm_proj_mfma<<<dim3(256), 256, 0, stream>>>(CTXs, Wps, b_proj, out);
}

// Round 8
// 271.622 us; speedup vs baseline: 2.3428x; 1.0486x over previous
//
#include <hip/hip_runtime.h>
#include <math.h>

constexpr int EMBED = 1024;
constexpr int HEADS = 16;
constexpr int HDIM  = 64;
constexpr int BATCH = 2;
constexpr int SEQ   = 2048;
constexpr int MTOT  = BATCH * SEQ;   // 4096
constexpr int KSPL  = 3 * EMBED;     // 3072: K' for the 3-term split GEMM
constexpr int LDK   = 2 * EMBED;     // 2048: physical [hi|lo] row width
constexpr int BHSZ  = SEQ * HDIM;    // 131072 elems per (b,h) slice

typedef unsigned short u16;
using bf16x8 = __attribute__((ext_vector_type(8))) short;
using f32x4  = __attribute__((ext_vector_type(4))) float;
using f32x16 = __attribute__((ext_vector_type(16))) float;
using u32x4  = __attribute__((ext_vector_type(4))) unsigned int;

__device__ __forceinline__ u16 f2bf(float f) {
    unsigned u = __builtin_bit_cast(unsigned, f);
    return (u16)((u + 0x7fffu + ((u >> 16) & 1u)) >> 16);
}
__device__ __forceinline__ float bf2f(u16 h) {
    unsigned u = ((unsigned)h) << 16;
    return __builtin_bit_cast(float, u);
}
__device__ __forceinline__ unsigned cvtpk(float lo, float hi) {
    unsigned r;
    asm("v_cvt_pk_bf16_f32 %0, %1, %2" : "=v"(r) : "v"(lo), "v"(hi));
    return r;
}

#define GLOAD16(gp, lp) __builtin_amdgcn_global_load_lds( \
    (const __attribute__((address_space(1))) unsigned int*)(gp), \
    (__attribute__((address_space(3))) unsigned int*)(lp), 16, 0, 0)

// Packed fragment layouts (per (b,h) slice of BHSZ elems):
//  Q/K: [tile=n/32][dt=d/16][lane=((d>>3)&1)*32 + n%32][j=d&7]
//  V:   [tile=n/32][dtv=d/32][kt=(n>>4)&1][lane=((n>>3)&1)*32 + d%32][j=n&7]

// ---------------------------------------------------------------------------
// Split f32 rows into bf16 [hi|lo]; w_qkv rows permuted to [which][h][d].
// ---------------------------------------------------------------------------
__global__ __launch_bounds__(256)
void convert_split(const float* __restrict__ X, const float* __restrict__ Wq,
                   const float* __restrict__ Wp,
                   u16* __restrict__ Xs, u16* __restrict__ Wqs, u16* __restrict__ Wps)
{
    int m = blockIdx.x;                 // 0..8191
    int k = threadIdx.x * 4;
    const float* src; u16* dst;
    if (m < 4096) {
        src = X + (size_t)m * EMBED;          dst = Xs + (size_t)m * LDK;
    } else if (m < 7168) {
        int f = m - 4096;
        int h = f / 192, rem = f - h * 192, d = rem / 3, wq = rem - d * 3;
        int nrow = wq * 1024 + h * 64 + d;
        src = Wq + (size_t)f * EMBED;         dst = Wqs + (size_t)nrow * LDK;
    } else {
        int lm = m - 7168;
        src = Wp + (size_t)lm * EMBED;        dst = Wps + (size_t)lm * LDK;
    }
    float4 v = *(const float4*)(src + k);
    ushort4 hi, lo;
    hi.x = f2bf(v.x); lo.x = f2bf(v.x - bf2f(hi.x));
    hi.y = f2bf(v.y); lo.y = f2bf(v.y - bf2f(hi.y));
    hi.z = f2bf(v.z); lo.z = f2bf(v.z - bf2f(hi.z));
    hi.w = f2bf(v.w); lo.w = f2bf(v.w - bf2f(hi.w));
    *(ushort4*)(dst + k)         = hi;
    *(ushort4*)(dst + EMBED + k) = lo;
}

// ---------------------------------------------------------------------------
// bf16 MFMA mainloop, K'=3072 remapped (A: [hi|lo|hi], B: [hi|hi|lo]).
// Depth-2 prefetch (3 LDS bufs, counted vmcnt(4)) + T2 bank-conflict swizzle:
// LDS dest stays LINEAR (global_load_lds requirement); the global SOURCE
// column-chunk is pre-swizzled and the ds_read applies the matching XOR
// (rule 21: source permutation == read permutation).
//   write: lane l stages G[R][ka + ((l&3) ^ ((l>>3)&3))*8] at linear slot l&3
//          (row R = rb + (l>>2); (R>>1)&3 == (l>>3)&3 since 16|rb)
//   read:  frag k-chunk kq=lane>>4 of row R lives at slot kq ^ ((R>>1)&3)
//          = kq ^ ((lane>>1)&3)  (lane-constant; banks 2-way max = free)
// ---------------------------------------------------------------------------
__device__ __forceinline__ void stage_pf(
    const u16* __restrict__ A, const u16* __restrict__ B,
    u16* As, u16* Bs, int buf, int t, int wid, int lane)
{
    const int k0 = t * 32;
    const int ka = k0 < 2048 ? k0 : k0 - 2048;
    const int kb = k0 < 1024 ? k0 : k0 - 1024;
    const int srow = lane >> 2;
    const int sc   = (((lane & 3) ^ ((lane >> 3) & 3))) * 8;   // swizzled src chunk
    u16* ab = As + buf * 4096;
    u16* bb = Bs + buf * 4096;
    #pragma unroll
    for (int i = 0; i < 2; ++i) {
        const int rb = wid * 32 + i * 16;
        GLOAD16(A + (size_t)(rb + srow) * LDK + ka + sc, ab + rb * 32);
        GLOAD16(B + (size_t)(rb + srow) * LDK + kb + sc, bb + rb * 32);
    }
}

__device__ __forceinline__ void mfma_loop_pf(
    const u16* __restrict__ Ab, const u16* __restrict__ Bb,
    u16* As, u16* Bs, f32x4 (&acc)[4][4], int wid, int lane)
{
    constexpr int NT = KSPL / 32;   // 96
    const int wr = wid >> 1, wc = wid & 1;
    const int frow = lane & 15;
    const int kg8s = (((lane >> 4) ^ ((lane >> 1) & 3))) * 8;  // swizzled read chunk

    stage_pf(Ab, Bb, As, Bs, 0, 0, wid, lane);
    stage_pf(Ab, Bb, As, Bs, 1, 1, wid, lane);
    asm volatile("s_waitcnt vmcnt(4)" ::: "memory");
    __builtin_amdgcn_s_barrier();
    __builtin_amdgcn_sched_barrier(0);

    int cb = 0, sb = 2;
    for (int t = 0; t < NT; ++t) {
        if (t + 2 < NT) stage_pf(Ab, Bb, As, Bs, sb, t + 2, wid, lane);
        const u16* ap = As + cb * 4096;
        const u16* bp = Bs + cb * 4096;
        bf16x8 a[4], b[4];
        #pragma unroll
        for (int mi = 0; mi < 4; ++mi)
            a[mi] = *(const bf16x8*)&ap[(wr * 64 + mi * 16 + frow) * 32 + kg8s];
        #pragma unroll
        for (int ni = 0; ni < 4; ++ni)
            b[ni] = *(const bf16x8*)&bp[(wc * 64 + ni * 16 + frow) * 32 + kg8s];
        #pragma unroll
        for (int mi = 0; mi < 4; ++mi)
            #pragma unroll
            for (int ni = 0; ni < 4; ++ni)
                acc[mi][ni] = __builtin_amdgcn_mfma_f32_16x16x32_bf16(
                    a[mi], b[ni], acc[mi][ni], 0, 0, 0);
        __builtin_amdgcn_sched_barrier(0);
        asm volatile("s_waitcnt lgkmcnt(0)" ::: "memory");
        if (t + 2 < NT) { asm volatile("s_waitcnt vmcnt(4)" ::: "memory"); }
        else            { asm volatile("s_waitcnt vmcnt(0)" ::: "memory"); }
        __builtin_amdgcn_s_barrier();
        __builtin_amdgcn_sched_barrier(0);
        cb = cb == 2 ? 0 : cb + 1;
        sb = sb == 2 ? 0 : sb + 1;
    }
}

// ---------------------------------------------------------------------------
// QKV GEMM: permuted weights -> each wave owns one (which, head).
// Epilogue: wave-private 64x64 LDS transpose -> coalesced packed stores.
// ---------------------------------------------------------------------------
__global__ __launch_bounds__(256)
void gemm_qkv_mfma(const u16* __restrict__ Xs, const u16* __restrict__ Wqs,
                   u16* __restrict__ Qhi, u16* __restrict__ Qlo,
                   u16* __restrict__ Khi, u16* __restrict__ Klo,
                   u16* __restrict__ Vt)
{
    __shared__ __align__(16) u16 SH[6 * 4096];   // 48 KB: As[3] | Bs[3]
    const int bid = blockIdx.x;                  // 768
    const int swz = (bid & 7) * 96 + (bid >> 3);
    const int bm  = swz & 31;
    const int bn  = swz >> 5;                    // 0..23
    const int wid = threadIdx.x >> 6, lane = threadIdx.x & 63;
    const int wr = wid >> 1, wc = wid & 1;

    f32x4 acc[4][4] = {};
    mfma_loop_pf(Xs + (size_t)bm * 128 * LDK, Wqs + (size_t)bn * 128 * LDK,
                 SH, SH + 3 * 4096, acc, wid, lane);

    const int which = bn >> 3;
    const int h     = ((bn & 7) << 1) | wc;
    const int b_    = bm >= 16;
    const size_t bhb = (size_t)(b_ * HEADS + h) * BHSZ;
    const int n0w = bm * 128 - b_ * SEQ + wr * 64;
    char* T = (char*)(SH + wid * 4096);

    if (which < 2) {
        u16* dstH = (which == 0 ? Qhi : Khi) + bhb;
        u16* dstL = (which == 0 ? Qlo : Klo) + bhb;
        #pragma unroll
        for (int pass = 0; pass < 2; ++pass) {
            u16* dst = pass ? dstL : dstH;
            #pragma unroll
            for (int mi = 0; mi < 4; ++mi)
                #pragma unroll
                for (int ni = 0; ni < 4; ++ni)
                    #pragma unroll
                    for (int r = 0; r < 4; ++r) {
                        float v = acc[mi][ni][r];
                        u16 hi = f2bf(v);
                        u16 ov = pass ? f2bf(v - bf2f(hi)) : hi;
                        int nl = ((lane >> 4) << 2) + mi * 16 + r;
                        int dl = ni * 16 + (lane & 15);
                        *(u16*)(T + nl * 128 + ((dl * 2) ^ ((nl & 7) << 4))) = ov;
                    }
            #pragma unroll
            for (int t2 = 0; t2 < 2; ++t2)
                #pragma unroll
                for (int dt = 0; dt < 4; ++dt) {
                    int nl   = t2 * 32 + (lane & 31);
                    int doff = (dt * 16 + (lane >> 5) * 8) * 2;
                    bf16x8 fr = *(const bf16x8*)(T + nl * 128 + (doff ^ ((nl & 7) << 4)));
                    int tile = (n0w >> 5) + t2;
                    *(bf16x8*)&dst[(size_t)(tile * 4 + dt) * 512 + lane * 8] = fr;
                }
        }
    } else {
        #pragma unroll
        for (int mi = 0; mi < 4; ++mi)
            #pragma unroll
            for (int ni = 0; ni < 4; ++ni)
                #pragma unroll
                for (int r = 0; r < 4; ++r) {
                    int nl = ((lane >> 4) << 2) + mi * 16 + r;
                    int dl = ni * 16 + (lane & 15);
                    *(u16*)(T + nl * 128 + ((dl * 2) ^ ((nl & 7) << 4))) =
                        f2bf(acc[mi][ni][r]);
                }
        u16* dst = Vt + bhb;
        #pragma unroll
        for (int t2 = 0; t2 < 2; ++t2)
            #pragma unroll
            for (int dtv = 0; dtv < 2; ++dtv)
                #pragma unroll
                for (int kt = 0; kt < 2; ++kt) {
                    int dcol = (dtv * 32 + (lane & 31)) * 2;
                    int nb   = t2 * 32 + kt * 16 + (lane >> 5) * 8;
                    bf16x8 fr;
                    #pragma unroll
                    for (int j = 0; j < 8; ++j) {
                        int nl = nb + j;
                        fr[j] = *(const short*)(T + nl * 128 + (dcol ^ ((nl & 7) << 4)));
                    }
                    int tile = (n0w >> 5) + t2;
                    *(bf16x8*)&dst[(size_t)(((tile * 2 + dtv) * 2 + kt) * 64 + lane) * 8] = fr;
                }
    }
}

__global__ __launch_bounds__(256)
void gemm_proj_mfma(const u16* __restrict__ CTXs, const u16* __restrict__ Wps,
                    const float* __restrict__ bias, float* __restrict__ Out)
{
    __shared__ __align__(16) u16 SH[6 * 4096];
    const int bid = blockIdx.x;                       // 256
    const int swz = (bid & 7) * 32 + (bid >> 3);
    const int bm  = swz & 31;
    const int bn  = swz >> 5;
    const int wid = threadIdx.x >> 6, lane = threadIdx.x & 63;
    const int wr = wid >> 1, wc = wid & 1;

    f32x4 acc[4][4] = {};
    mfma_loop_pf(CTXs + (size_t)bm * 128 * LDK, Wps + (size_t)bn * 128 * LDK,
                 SH, SH + 3 * 4096, acc, wid, lane);

    const int m0 = bm * 128 + wr * 64 + ((lane >> 4) << 2);
    #pragma unroll
    for (int ni = 0; ni < 4; ++ni) {
        const int f  = bn * 128 + wc * 64 + ni * 16 + (lane & 15);
        const float bv = bias[f];
        #pragma unroll
        for (int mi = 0; mi < 4; ++mi) {
            const int m = m0 + mi * 16;
            #pragma unroll
            for (int r = 0; r < 4; ++r)
                Out[(size_t)(m + r) * EMBED + f] = fmaxf(acc[mi][ni][r] + bv, 0.f);
        }
    }
}

// ---------------------------------------------------------------------------
// Flash attention (unchanged from R6/R7).
// ---------------------------------------------------------------------------
__global__ __launch_bounds__(256)
void attn_mfma(const u16* __restrict__ Qhi, const u16* __restrict__ Qlo,
               const u16* __restrict__ Khi, const u16* __restrict__ Klo,
               const u16* __restrict__ Vt,  u16* __restrict__ CTXs)
{
    __shared__ __align__(16) float Lot[2][64][33];
    __shared__ float Lml[2][2][32];
    __shared__ __align__(16) float Ol[2][32][68];

    const int bid  = blockIdx.x;                     // 1024
    const int swz  = (bid & 7) * 128 + (bid >> 3);
    const int bh   = swz >> 5;
    const int qp   = swz & 31;
    const int wid  = threadIdx.x >> 6;
    const int lane = threadIdx.x & 63;
    const int col  = lane & 31;
    const int g    = lane >> 5;
    const int qt   = wid >> 1;
    const int kh   = wid & 1;

    const int q0   = qp * 64 + qt * 32;
    const int b_   = bh / HEADS;
    const int h    = bh % HEADS;
    const int tbeg = kh * (SEQ / 2 / 32);
    const int tend = tbeg + SEQ / 2 / 32;

    const size_t bhb = (size_t)bh * BHSZ;
    const u16* kb_hi = Khi + bhb + (size_t)lane * 8;
    const u16* kb_lo = Klo + bhb + (size_t)lane * 8;
    const u16* vb    = Vt  + bhb + (size_t)lane * 8;

    bf16x8 qh[4], ql[4];
    {
        const u16* qbh = Qhi + bhb + (size_t)(q0 >> 5) * 2048 + (size_t)lane * 8;
        const u16* qbl = Qlo + bhb + (size_t)(q0 >> 5) * 2048 + (size_t)lane * 8;
        #pragma unroll
        for (int dt = 0; dt < 4; ++dt) {
            qh[dt] = *(const bf16x8*)(qbh + dt * 512);
            ql[dt] = *(const bf16x8*)(qbl + dt * 512);
        }
    }

    f32x16 ot0 = {}, ot1 = {};
    float m_run = -3.0e38f, l_run = 0.0f;

    bf16x8 kfh[4], kfl[4];
    #pragma unroll
    for (int dt = 0; dt < 4; ++dt) {
        kfh[dt] = *(const bf16x8*)(kb_hi + (size_t)tbeg * 2048 + dt * 512);
        kfl[dt] = *(const bf16x8*)(kb_lo + (size_t)tbeg * 2048 + dt * 512);
    }

    for (int t = tbeg; t < tend; ++t) {
        bf16x8 vf[2][2];
        #pragma unroll
        for (int dt = 0; dt < 2; ++dt)
            #pragma unroll
            for (int kt = 0; kt < 2; ++kt)
                vf[dt][kt] = *(const bf16x8*)(vb + (size_t)t * 2048 + dt * 1024 + kt * 512);

        bf16x8 nkh[4], nkl[4];
        const bool more = (t + 1) < tend;
        if (more) {
            #pragma unroll
            for (int dt = 0; dt < 4; ++dt) {
                nkh[dt] = *(const bf16x8*)(kb_hi + (size_t)(t + 1) * 2048 + dt * 512);
                nkl[dt] = *(const bf16x8*)(kb_lo + (size_t)(t + 1) * 2048 + dt * 512);
            }
        }

        f32x16 st = {};
        #pragma unroll
        for (int dt = 0; dt < 4; ++dt) {
            st = __builtin_amdgcn_mfma_f32_32x32x16_bf16(kfh[dt], qh[dt], st, 0, 0, 0);
            st = __builtin_amdgcn_mfma_f32_32x32x16_bf16(kfh[dt], ql[dt], st, 0, 0, 0);
            st = __builtin_amdgcn_mfma_f32_32x32x16_bf16(kfl[dt], qh[dt], st, 0, 0, 0);
        }

        float mx;
        {
            float m0 = fmaxf(fmaxf(st[0], st[1]),  fmaxf(st[2], st[3]));
            float m1 = fmaxf(fmaxf(st[4], st[5]),  fmaxf(st[6], st[7]));
            float m2 = fmaxf(fmaxf(st[8], st[9]),  fmaxf(st[10], st[11]));
            float m3 = fmaxf(fmaxf(st[12], st[13]), fmaxf(st[14], st[15]));
            mx = fmaxf(fmaxf(m0, m1), fmaxf(m2, m3));
        }
        mx = fmaxf(mx, __shfl_xor(mx, 32));
        if (__ballot(mx > m_run + 8.0f)) {
            float m_new = fmaxf(m_run, mx);
            float corr  = __expf(m_run - m_new);
            l_run *= corr;
            ot0 = ot0 * corr;
            ot1 = ot1 * corr;
            m_run = m_new;
        }

        float p[16];
        #pragma unroll
        for (int r = 0; r < 16; ++r) p[r] = __expf(st[r] - m_run);
        {
            float s0 = (p[0] + p[1]) + (p[2] + p[3]);
            float s1 = (p[4] + p[5]) + (p[6] + p[7]);
            float s2 = (p[8] + p[9]) + (p[10] + p[11]);
            float s3 = (p[12] + p[13]) + (p[14] + p[15]);
            float ps = (s0 + s1) + (s2 + s3);
            ps += __shfl_xor(ps, 32);
            l_run += ps;
        }

        unsigned W0 = cvtpk(p[0],  p[1]),  W1 = cvtpk(p[2],  p[3]);
        unsigned W2 = cvtpk(p[4],  p[5]),  W3 = cvtpk(p[6],  p[7]);
        unsigned W4 = cvtpk(p[8],  p[9]),  W5 = cvtpk(p[10], p[11]);
        unsigned W6 = cvtpk(p[12], p[13]), W7 = cvtpk(p[14], p[15]);
        asm("v_permlane32_swap_b32 %0, %1" : "+v"(W0), "+v"(W2));
        asm("v_permlane32_swap_b32 %0, %1" : "+v"(W1), "+v"(W3));
        asm("v_permlane32_swap_b32 %0, %1" : "+v"(W4), "+v"(W6));
        asm("v_permlane32_swap_b32 %0, %1" : "+v"(W5), "+v"(W7));
        u32x4 t0 = {W0, W1, W2, W3};
        u32x4 t1 = {W4, W5, W6, W7};
        bf16x8 pf0 = __builtin_bit_cast(bf16x8, t0);
        bf16x8 pf1 = __builtin_bit_cast(bf16x8, t1);

        ot0 = __builtin_amdgcn_mfma_f32_32x32x16_bf16(vf[0][0], pf0, ot0, 0, 0, 0);
        ot1 = __builtin_amdgcn_mfma_f32_32x32x16_bf16(vf[1][0], pf0, ot1, 0, 0, 0);
        ot0 = __builtin_amdgcn_mfma_f32_32x32x16_bf16(vf[0][1], pf1, ot0, 0, 0, 0);
        ot1 = __builtin_amdgcn_mfma_f32_32x32x16_bf16(vf[1][1], pf1, ot1, 0, 0, 0);

        if (more) {
            #pragma unroll
            for (int dt = 0; dt < 4; ++dt) { kfh[dt] = nkh[dt]; kfl[dt] = nkl[dt]; }
        }
    }

    if (kh == 1) {
        #pragma unroll
        for (int r = 0; r < 16; ++r) {
            int d = (r & 3) + 8 * (r >> 2) + 4 * g;
            Lot[qt][d][col]      = ot0[r];
            Lot[qt][d + 32][col] = ot1[r];
        }
        if (g == 0) { Lml[qt][0][col] = m_run; Lml[qt][1][col] = l_run; }
    }
    __syncthreads();
    if (kh == 0) {
        float m1 = Lml[qt][0][col], l1 = Lml[qt][1][col];
        float m  = fmaxf(m_run, m1);
        float c0 = __expf(m_run - m), c1 = __expf(m1 - m);
        float l  = l_run * c0 + l1 * c1;
        float sc0 = c0 / (l * 32.0f);
        float sc1 = c1 / (l * 32.0f);
        #pragma unroll
        for (int r = 0; r < 16; ++r) {
            int d = (r & 3) + 8 * (r >> 2) + 4 * g;
            Ol[qt][col][d]      = ot0[r] * sc0 + Lot[qt][d][col] * sc1;
            Ol[qt][col][d + 32] = ot1[r] * sc0 + Lot[qt][d + 32][col] * sc1;
        }
        #pragma unroll
        for (int pass = 0; pass < 8; ++pass) {
            int qq = pass * 4 + (lane >> 4);
            int dd = (lane & 15) * 4;
            float4 t = *(const float4*)&Ol[qt][qq][dd];
            int m_ = b_ * SEQ + q0 + qq;
            ushort4 hv, lv;
            hv.x = f2bf(t.x); lv.x = f2bf(t.x - bf2f(hv.x));
            hv.y = f2bf(t.y); lv.y = f2bf(t.y - bf2f(hv.y));
            hv.z = f2bf(t.z); lv.z = f2bf(t.z - bf2f(hv.z));
            hv.w = f2bf(t.w); lv.w = f2bf(t.w - bf2f(hv.w));
            *(ushort4*)&CTXs[(size_t)m_ * LDK + h * HDIM + dd]         = hv;
            *(ushort4*)&CTXs[(size_t)m_ * LDK + EMBED + h * HDIM + dd] = lv;
        }
    }
}

extern "C" void kernel_launch(void* const* d_in, const int* in_sizes, int n_in,
                              void* d_out, int out_size, void* d_ws, size_t ws_size,
                              hipStream_t stream)
{
    const float* x      = (const float*)d_in[0];
    const float* w_qkv  = (const float*)d_in[1];
    const float* w_proj = (const float*)d_in[2];
    const float* b_proj = (const float*)d_in[3];
    float* out = (float*)d_out;

    const size_t seg = (size_t)BATCH * HEADS * SEQ * HDIM;   // 4 Mi elems
    char* w = (char*)d_ws;
    u16* Xs   = (u16*)w;  w += (size_t)MTOT * LDK * 2;       // 16 MiB
    u16* Wqs  = (u16*)w;  w += (size_t)3 * EMBED * LDK * 2;  // 12 MiB
    u16* Wps  = (u16*)w;  w += (size_t)EMBED * LDK * 2;      // 4 MiB
    u16* Qhi  = (u16*)w;  w += seg * 2;
    u16* Qlo  = (u16*)w;  w += seg * 2;
    u16* Khi  = (u16*)w;  w += seg * 2;
    u16* Klo  = (u16*)w;  w += seg * 2;
    u16* Vt   = (u16*)w;  w += seg * 2;
    u16* CTXs = Xs;   // Xs dead after gemm_qkv_mfma

    convert_split<<<dim3(8192), 256, 0, stream>>>(x, w_qkv, w_proj, Xs, Wqs, Wps);
    gemm_qkv_mfma<<<dim3(768), 256, 0, stream>>>(Xs, Wqs, Qhi, Qlo, Khi, Klo, Vt);
    attn_mfma<<<dim3(1024), 256, 0, stream>>>(Qhi, Qlo, Khi, Klo, Vt, CTXs);
    gemm_proj_mfma<<<dim3(256), 256, 0, stream>>>(CTXs, Wps, b_proj, out);
}

// Round 9
// 270.401 us; speedup vs baseline: 2.3534x; 1.0045x over previous
//
#include <hip/hip_runtime.h>
#include <math.h>

constexpr int EMBED = 1024;
constexpr int HEADS = 16;
constexpr int HDIM  = 64;
constexpr int BATCH = 2;
constexpr int SEQ   = 2048;
constexpr int MTOT  = BATCH * SEQ;   // 4096
constexpr int KSPL  = 3 * EMBED;     // 3072: K' for the 3-term split GEMM
constexpr int LDK   = 2 * EMBED;     // 2048: physical [hi|lo] row width
constexpr int BHSZ  = SEQ * HDIM;    // 131072 elems per (b,h) slice

typedef unsigned short u16;
using bf16x8 = __attribute__((ext_vector_type(8))) short;
using f32x4  = __attribute__((ext_vector_type(4))) float;
using f32x16 = __attribute__((ext_vector_type(16))) float;
using u32x4  = __attribute__((ext_vector_type(4))) unsigned int;

__device__ __forceinline__ u16 f2bf(float f) {
    unsigned u = __builtin_bit_cast(unsigned, f);
    return (u16)((u + 0x7fffu + ((u >> 16) & 1u)) >> 16);
}
__device__ __forceinline__ float bf2f(u16 h) {
    unsigned u = ((unsigned)h) << 16;
    return __builtin_bit_cast(float, u);
}
__device__ __forceinline__ unsigned cvtpk(float lo, float hi) {
    unsigned r;
    asm("v_cvt_pk_bf16_f32 %0, %1, %2" : "=v"(r) : "v"(lo), "v"(hi));
    return r;
}

#define GLOAD16(gp, lp) __builtin_amdgcn_global_load_lds( \
    (const __attribute__((address_space(1))) unsigned int*)(gp), \
    (__attribute__((address_space(3))) unsigned int*)(lp), 16, 0, 0)

// Packed fragment layouts (per (b,h) slice of BHSZ elems):
//  Q/K: [tile=n/32][dt=d/16][lane=((d>>3)&1)*32 + n%32][j=d&7]
//  V:   [tile=n/32][dtv=d/32][kt=(n>>4)&1][lane=((n>>3)&1)*32 + d%32][j=n&7]

// ---------------------------------------------------------------------------
// Split f32 rows into bf16 [hi|lo]; w_qkv rows permuted to [which][h][d].
// ---------------------------------------------------------------------------
__global__ __launch_bounds__(256)
void convert_split(const float* __restrict__ X, const float* __restrict__ Wq,
                   const float* __restrict__ Wp,
                   u16* __restrict__ Xs, u16* __restrict__ Wqs, u16* __restrict__ Wps)
{
    int m = blockIdx.x;                 // 0..8191
    int k = threadIdx.x * 4;
    const float* src; u16* dst;
    if (m < 4096) {
        src = X + (size_t)m * EMBED;          dst = Xs + (size_t)m * LDK;
    } else if (m < 7168) {
        int f = m - 4096;
        int h = f / 192, rem = f - h * 192, d = rem / 3, wq = rem - d * 3;
        int nrow = wq * 1024 + h * 64 + d;
        src = Wq + (size_t)f * EMBED;         dst = Wqs + (size_t)nrow * LDK;
    } else {
        int lm = m - 7168;
        src = Wp + (size_t)lm * EMBED;        dst = Wps + (size_t)lm * LDK;
    }
    float4 v = *(const float4*)(src + k);
    ushort4 hi, lo;
    hi.x = f2bf(v.x); lo.x = f2bf(v.x - bf2f(hi.x));
    hi.y = f2bf(v.y); lo.y = f2bf(v.y - bf2f(hi.y));
    hi.z = f2bf(v.z); lo.z = f2bf(v.z - bf2f(hi.z));
    hi.w = f2bf(v.w); lo.w = f2bf(v.w - bf2f(hi.w));
    *(ushort4*)(dst + k)         = hi;
    *(ushort4*)(dst + EMBED + k) = lo;
}

// ---------------------------------------------------------------------------
// bf16 MFMA mainloop, K'=3072 remapped (A: [hi|lo|hi], B: [hi|hi|lo]).
// Depth-2 prefetch (3 LDS bufs, counted vmcnt(4)) + T2 source-swizzle
// (conflict-free ds_read, verified R8: 9.5M -> 131K conflicts).
// ---------------------------------------------------------------------------
__device__ __forceinline__ void stage_pf(
    const u16* __restrict__ A, const u16* __restrict__ B,
    u16* As, u16* Bs, int buf, int t, int wid, int lane)
{
    const int k0 = t * 32;
    const int ka = k0 < 2048 ? k0 : k0 - 2048;
    const int kb = k0 < 1024 ? k0 : k0 - 1024;
    const int srow = lane >> 2;
    const int sc   = (((lane & 3) ^ ((lane >> 3) & 3))) * 8;   // swizzled src chunk
    u16* ab = As + buf * 4096;
    u16* bb = Bs + buf * 4096;
    #pragma unroll
    for (int i = 0; i < 2; ++i) {
        const int rb = wid * 32 + i * 16;
        GLOAD16(A + (size_t)(rb + srow) * LDK + ka + sc, ab + rb * 32);
        GLOAD16(B + (size_t)(rb + srow) * LDK + kb + sc, bb + rb * 32);
    }
}

__device__ __forceinline__ void mfma_loop_pf(
    const u16* __restrict__ Ab, const u16* __restrict__ Bb,
    u16* As, u16* Bs, f32x4 (&acc)[4][4], int wid, int lane)
{
    constexpr int NT = KSPL / 32;   // 96
    const int wr = wid >> 1, wc = wid & 1;
    const int frow = lane & 15;
    const int kg8s = (((lane >> 4) ^ ((lane >> 1) & 3))) * 8;  // swizzled read chunk

    stage_pf(Ab, Bb, As, Bs, 0, 0, wid, lane);
    stage_pf(Ab, Bb, As, Bs, 1, 1, wid, lane);
    asm volatile("s_waitcnt vmcnt(4)" ::: "memory");
    __builtin_amdgcn_s_barrier();
    __builtin_amdgcn_sched_barrier(0);

    int cb = 0, sb = 2;
    for (int t = 0; t < NT; ++t) {
        if (t + 2 < NT) stage_pf(Ab, Bb, As, Bs, sb, t + 2, wid, lane);
        const u16* ap = As + cb * 4096;
        const u16* bp = Bs + cb * 4096;
        bf16x8 a[4], b[4];
        #pragma unroll
        for (int mi = 0; mi < 4; ++mi)
            a[mi] = *(const bf16x8*)&ap[(wr * 64 + mi * 16 + frow) * 32 + kg8s];
        #pragma unroll
        for (int ni = 0; ni < 4; ++ni)
            b[ni] = *(const bf16x8*)&bp[(wc * 64 + ni * 16 + frow) * 32 + kg8s];
        #pragma unroll
        for (int mi = 0; mi < 4; ++mi)
            #pragma unroll
            for (int ni = 0; ni < 4; ++ni)
                acc[mi][ni] = __builtin_amdgcn_mfma_f32_16x16x32_bf16(
                    a[mi], b[ni], acc[mi][ni], 0, 0, 0);
        __builtin_amdgcn_sched_barrier(0);
        asm volatile("s_waitcnt lgkmcnt(0)" ::: "memory");
        if (t + 2 < NT) { asm volatile("s_waitcnt vmcnt(4)" ::: "memory"); }
        else            { asm volatile("s_waitcnt vmcnt(0)" ::: "memory"); }
        __builtin_amdgcn_s_barrier();
        __builtin_amdgcn_sched_barrier(0);
        cb = cb == 2 ? 0 : cb + 1;
        sb = sb == 2 ? 0 : sb + 1;
    }
}

// ---------------------------------------------------------------------------
// QKV GEMM. 2-D XCD-blocked grid map (R9): XCD x = bid&7 owns bm in
// [4x,4x+4) x all bn; within-XCD order j = bid>>3: bm = 4x+(j&3), bn = j>>2.
// Concurrent blocks per XCD span 4 bm x ~3 bn = 3.5 MB working set < 4 MiB L2
// (R8 map gave every XCD all 32 bm = 16 MB -> 304 MB HBM overfetch).
// ---------------------------------------------------------------------------
__global__ __launch_bounds__(256)
void gemm_qkv_mfma(const u16* __restrict__ Xs, const u16* __restrict__ Wqs,
                   u16* __restrict__ Qhi, u16* __restrict__ Qlo,
                   u16* __restrict__ Khi, u16* __restrict__ Klo,
                   u16* __restrict__ Vt)
{
    __shared__ __align__(16) u16 SH[6 * 4096];   // 48 KB: As[3] | Bs[3]
    const int bid = blockIdx.x;                  // 768
    const int xcd = bid & 7, j = bid >> 3;       // j in [0,96)
    const int bm  = xcd * 4 + (j & 3);           // 0..31
    const int bn  = j >> 2;                      // 0..23
    const int wid = threadIdx.x >> 6, lane = threadIdx.x & 63;
    const int wr = wid >> 1, wc = wid & 1;

    f32x4 acc[4][4] = {};
    mfma_loop_pf(Xs + (size_t)bm * 128 * LDK, Wqs + (size_t)bn * 128 * LDK,
                 SH, SH + 3 * 4096, acc, wid, lane);

    const int which = bn >> 3;
    const int h     = ((bn & 7) << 1) | wc;
    const int b_    = bm >= 16;
    const size_t bhb = (size_t)(b_ * HEADS + h) * BHSZ;
    const int n0w = bm * 128 - b_ * SEQ + wr * 64;
    char* T = (char*)(SH + wid * 4096);

    if (which < 2) {
        u16* dstH = (which == 0 ? Qhi : Khi) + bhb;
        u16* dstL = (which == 0 ? Qlo : Klo) + bhb;
        #pragma unroll
        for (int pass = 0; pass < 2; ++pass) {
            u16* dst = pass ? dstL : dstH;
            #pragma unroll
            for (int mi = 0; mi < 4; ++mi)
                #pragma unroll
                for (int ni = 0; ni < 4; ++ni)
                    #pragma unroll
                    for (int r = 0; r < 4; ++r) {
                        float v = acc[mi][ni][r];
                        u16 hi = f2bf(v);
                        u16 ov = pass ? f2bf(v - bf2f(hi)) : hi;
                        int nl = ((lane >> 4) << 2) + mi * 16 + r;
                        int dl = ni * 16 + (lane & 15);
                        *(u16*)(T + nl * 128 + ((dl * 2) ^ ((nl & 7) << 4))) = ov;
                    }
            #pragma unroll
            for (int t2 = 0; t2 < 2; ++t2)
                #pragma unroll
                for (int dt = 0; dt < 4; ++dt) {
                    int nl   = t2 * 32 + (lane & 31);
                    int doff = (dt * 16 + (lane >> 5) * 8) * 2;
                    bf16x8 fr = *(const bf16x8*)(T + nl * 128 + (doff ^ ((nl & 7) << 4)));
                    int tile = (n0w >> 5) + t2;
                    *(bf16x8*)&dst[(size_t)(tile * 4 + dt) * 512 + lane * 8] = fr;
                }
        }
    } else {
        #pragma unroll
        for (int mi = 0; mi < 4; ++mi)
            #pragma unroll
            for (int ni = 0; ni < 4; ++ni)
                #pragma unroll
                for (int r = 0; r < 4; ++r) {
                    int nl = ((lane >> 4) << 2) + mi * 16 + r;
                    int dl = ni * 16 + (lane & 15);
                    *(u16*)(T + nl * 128 + ((dl * 2) ^ ((nl & 7) << 4))) =
                        f2bf(acc[mi][ni][r]);
                }
        u16* dst = Vt + bhb;
        #pragma unroll
        for (int t2 = 0; t2 < 2; ++t2)
            #pragma unroll
            for (int dtv = 0; dtv < 2; ++dtv)
                #pragma unroll
                for (int kt = 0; kt < 2; ++kt) {
                    int dcol = (dtv * 32 + (lane & 31)) * 2;
                    int nb   = t2 * 32 + kt * 16 + (lane >> 5) * 8;
                    bf16x8 fr;
                    #pragma unroll
                    for (int j2 = 0; j2 < 8; ++j2) {
                        int nl = nb + j2;
                        fr[j2] = *(const short*)(T + nl * 128 + (dcol ^ ((nl & 7) << 4)));
                    }
                    int tile = (n0w >> 5) + t2;
                    *(bf16x8*)&dst[(size_t)(((tile * 2 + dtv) * 2 + kt) * 64 + lane) * 8] = fr;
                }
    }
}

__global__ __launch_bounds__(256)
void gemm_proj_mfma(const u16* __restrict__ CTXs, const u16* __restrict__ Wps,
                    const float* __restrict__ bias, float* __restrict__ Out)
{
    __shared__ __align__(16) u16 SH[6 * 4096];
    const int bid = blockIdx.x;                  // 256
    const int xcd = bid & 7, j = bid >> 3;       // j in [0,32)
    const int bm  = xcd * 4 + (j & 3);           // 0..31
    const int bn  = j >> 2;                      // 0..7
    const int wid = threadIdx.x >> 6, lane = threadIdx.x & 63;
    const int wr = wid >> 1, wc = wid & 1;

    f32x4 acc[4][4] = {};
    mfma_loop_pf(CTXs + (size_t)bm * 128 * LDK, Wps + (size_t)bn * 128 * LDK,
                 SH, SH + 3 * 4096, acc, wid, lane);

    const int m0 = bm * 128 + wr * 64 + ((lane >> 4) << 2);
    #pragma unroll
    for (int ni = 0; ni < 4; ++ni) {
        const int f  = bn * 128 + wc * 64 + ni * 16 + (lane & 15);
        const float bv = bias[f];
        #pragma unroll
        for (int mi = 0; mi < 4; ++mi) {
            const int m = m0 + mi * 16;
            #pragma unroll
            for (int r = 0; r < 4; ++r)
                Out[(size_t)(m + r) * EMBED + f] = fmaxf(acc[mi][ni][r] + bv, 0.f);
        }
    }
}

// ---------------------------------------------------------------------------
// Flash attention (unchanged from R6-R8).
// ---------------------------------------------------------------------------
__global__ __launch_bounds__(256)
void attn_mfma(const u16* __restrict__ Qhi, const u16* __restrict__ Qlo,
               const u16* __restrict__ Khi, const u16* __restrict__ Klo,
               const u16* __restrict__ Vt,  u16* __restrict__ CTXs)
{
    __shared__ __align__(16) float Lot[2][64][33];
    __shared__ float Lml[2][2][32];
    __shared__ __align__(16) float Ol[2][32][68];

    const int bid  = blockIdx.x;                     // 1024
    const int swz  = (bid & 7) * 128 + (bid >> 3);
    const int bh   = swz >> 5;
    const int qp   = swz & 31;
    const int wid  = threadIdx.x >> 6;
    const int lane = threadIdx.x & 63;
    const int col  = lane & 31;
    const int g    = lane >> 5;
    const int qt   = wid >> 1;
    const int kh   = wid & 1;

    const int q0   = qp * 64 + qt * 32;
    const int b_   = bh / HEADS;
    const int h    = bh % HEADS;
    const int tbeg = kh * (SEQ / 2 / 32);
    const int tend = tbeg + SEQ / 2 / 32;

    const size_t bhb = (size_t)bh * BHSZ;
    const u16* kb_hi = Khi + bhb + (size_t)lane * 8;
    const u16* kb_lo = Klo + bhb + (size_t)lane * 8;
    const u16* vb    = Vt  + bhb + (size_t)lane * 8;

    bf16x8 qh[4], ql[4];
    {
        const u16* qbh = Qhi + bhb + (size_t)(q0 >> 5) * 2048 + (size_t)lane * 8;
        const u16* qbl = Qlo + bhb + (size_t)(q0 >> 5) * 2048 + (size_t)lane * 8;
        #pragma unroll
        for (int dt = 0; dt < 4; ++dt) {
            qh[dt] = *(const bf16x8*)(qbh + dt * 512);
            ql[dt] = *(const bf16x8*)(qbl + dt * 512);
        }
    }

    f32x16 ot0 = {}, ot1 = {};
    float m_run = -3.0e38f, l_run = 0.0f;

    bf16x8 kfh[4], kfl[4];
    #pragma unroll
    for (int dt = 0; dt < 4; ++dt) {
        kfh[dt] = *(const bf16x8*)(kb_hi + (size_t)tbeg * 2048 + dt * 512);
        kfl[dt] = *(const bf16x8*)(kb_lo + (size_t)tbeg * 2048 + dt * 512);
    }

    for (int t = tbeg; t < tend; ++t) {
        bf16x8 vf[2][2];
        #pragma unroll
        for (int dt = 0; dt < 2; ++dt)
            #pragma unroll
            for (int kt = 0; kt < 2; ++kt)
                vf[dt][kt] = *(const bf16x8*)(vb + (size_t)t * 2048 + dt * 1024 + kt * 512);

        bf16x8 nkh[4], nkl[4];
        const bool more = (t + 1) < tend;
        if (more) {
            #pragma unroll
            for (int dt = 0; dt < 4; ++dt) {
                nkh[dt] = *(const bf16x8*)(kb_hi + (size_t)(t + 1) * 2048 + dt * 512);
                nkl[dt] = *(const bf16x8*)(kb_lo + (size_t)(t + 1) * 2048 + dt * 512);
            }
        }

        f32x16 st = {};
        #pragma unroll
        for (int dt = 0; dt < 4; ++dt) {
            st = __builtin_amdgcn_mfma_f32_32x32x16_bf16(kfh[dt], qh[dt], st, 0, 0, 0);
            st = __builtin_amdgcn_mfma_f32_32x32x16_bf16(kfh[dt], ql[dt], st, 0, 0, 0);
            st = __builtin_amdgcn_mfma_f32_32x32x16_bf16(kfl[dt], qh[dt], st, 0, 0, 0);
        }

        float mx;
        {
            float m0 = fmaxf(fmaxf(st[0], st[1]),  fmaxf(st[2], st[3]));
            float m1 = fmaxf(fmaxf(st[4], st[5]),  fmaxf(st[6], st[7]));
            float m2 = fmaxf(fmaxf(st[8], st[9]),  fmaxf(st[10], st[11]));
            float m3 = fmaxf(fmaxf(st[12], st[13]), fmaxf(st[14], st[15]));
            mx = fmaxf(fmaxf(m0, m1), fmaxf(m2, m3));
        }
        mx = fmaxf(mx, __shfl_xor(mx, 32));
        if (__ballot(mx > m_run + 8.0f)) {
            float m_new = fmaxf(m_run, mx);
            float corr  = __expf(m_run - m_new);
            l_run *= corr;
            ot0 = ot0 * corr;
            ot1 = ot1 * corr;
            m_run = m_new;
        }

        float p[16];
        #pragma unroll
        for (int r = 0; r < 16; ++r) p[r] = __expf(st[r] - m_run);
        {
            float s0 = (p[0] + p[1]) + (p[2] + p[3]);
            float s1 = (p[4] + p[5]) + (p[6] + p[7]);
            float s2 = (p[8] + p[9]) + (p[10] + p[11]);
            float s3 = (p[12] + p[13]) + (p[14] + p[15]);
            float ps = (s0 + s1) + (s2 + s3);
            ps += __shfl_xor(ps, 32);
            l_run += ps;
        }

        unsigned W0 = cvtpk(p[0],  p[1]),  W1 = cvtpk(p[2],  p[3]);
        unsigned W2 = cvtpk(p[4],  p[5]),  W3 = cvtpk(p[6],  p[7]);
        unsigned W4 = cvtpk(p[8],  p[9]),  W5 = cvtpk(p[10], p[11]);
        unsigned W6 = cvtpk(p[12], p[13]), W7 = cvtpk(p[14], p[15]);
        asm("v_permlane32_swap_b32 %0, %1" : "+v"(W0), "+v"(W2));
        asm("v_permlane32_swap_b32 %0, %1" : "+v"(W1), "+v"(W3));
        asm("v_permlane32_swap_b32 %0, %1" : "+v"(W4), "+v"(W6));
        asm("v_permlane32_swap_b32 %0, %1" : "+v"(W5), "+v"(W7));
        u32x4 t0 = {W0, W1, W2, W3};
        u32x4 t1 = {W4, W5, W6, W7};
        bf16x8 pf0 = __builtin_bit_cast(bf16x8, t0);
        bf16x8 pf1 = __builtin_bit_cast(bf16x8, t1);

        ot0 = __builtin_amdgcn_mfma_f32_32x32x16_bf16(vf[0][0], pf0, ot0, 0, 0, 0);
        ot1 = __builtin_amdgcn_mfma_f32_32x32x16_bf16(vf[1][0], pf0, ot1, 0, 0, 0);
        ot0 = __builtin_amdgcn_mfma_f32_32x32x16_bf16(vf[0][1], pf1, ot0, 0, 0, 0);
        ot1 = __builtin_amdgcn_mfma_f32_32x32x16_bf16(vf[1][1], pf1, ot1, 0, 0, 0);

        if (more) {
            #pragma unroll
            for (int dt = 0; dt < 4; ++dt) { kfh[dt] = nkh[dt]; kfl[dt] = nkl[dt]; }
        }
    }

    if (kh == 1) {
        #pragma unroll
        for (int r = 0; r < 16; ++r) {
            int d = (r & 3) + 8 * (r >> 2) + 4 * g;
            Lot[qt][d][col]      = ot0[r];
            Lot[qt][d + 32][col] = ot1[r];
        }
        if (g == 0) { Lml[qt][0][col] = m_run; Lml[qt][1][col] = l_run; }
    }
    __syncthreads();
    if (kh == 0) {
        float m1 = Lml[qt][0][col], l1 = Lml[qt][1][col];
        float m  = fmaxf(m_run, m1);
        float c0 = __expf(m_run - m), c1 = __expf(m1 - m);
        float l  = l_run * c0 + l1 * c1;
        float sc0 = c0 / (l * 32.0f);
        float sc1 = c1 / (l * 32.0f);
        #pragma unroll
        for (int r = 0; r < 16; ++r) {
            int d = (r & 3) + 8 * (r >> 2) + 4 * g;
            Ol[qt][col][d]      = ot0[r] * sc0 + Lot[qt][d][col] * sc1;
            Ol[qt][col][d + 32] = ot1[r] * sc0 + Lot[qt][d + 32][col] * sc1;
        }
        #pragma unroll
        for (int pass = 0; pass < 8; ++pass) {
            int qq = pass * 4 + (lane >> 4);
            int dd = (lane & 15) * 4;
            float4 t = *(const float4*)&Ol[qt][qq][dd];
            int m_ = b_ * SEQ + q0 + qq;
            ushort4 hv, lv;
            hv.x = f2bf(t.x); lv.x = f2bf(t.x - bf2f(hv.x));
            hv.y = f2bf(t.y); lv.y = f2bf(t.y - bf2f(hv.y));
            hv.z = f2bf(t.z); lv.z = f2bf(t.z - bf2f(hv.z));
            hv.w = f2bf(t.w); lv.w = f2bf(t.w - bf2f(hv.w));
            *(ushort4*)&CTXs[(size_t)m_ * LDK + h * HDIM + dd]         = hv;
            *(ushort4*)&CTXs[(size_t)m_ * LDK + EMBED + h * HDIM + dd] = lv;
        }
    }
}

extern "C" void kernel_launch(void* const* d_in, const int* in_sizes, int n_in,
                              void* d_out, int out_size, void* d_ws, size_t ws_size,
                              hipStream_t stream)
{
    const float* x      = (const float*)d_in[0];
    const float* w_qkv  = (const float*)d_in[1];
    const float* w_proj = (const float*)d_in[2];
    const float* b_proj = (const float*)d_in[3];
    float* out = (float*)d_out;

    const size_t seg = (size_t)BATCH * HEADS * SEQ * HDIM;   // 4 Mi elems
    char* w = (char*)d_ws;
    u16* Xs   = (u16*)w;  w += (size_t)MTOT * LDK * 2;       // 16 MiB
    u16* Wqs  = (u16*)w;  w += (size_t)3 * EMBED * LDK * 2;  // 12 MiB
    u16* Wps  = (u16*)w;  w += (size_t)EMBED * LDK * 2;      // 4 MiB
    u16* Qhi  = (u16*)w;  w += seg * 2;
    u16* Qlo  = (u16*)w;  w += seg * 2;
    u16* Khi  = (u16*)w;  w += seg * 2;
    u16* Klo  = (u16*)w;  w += seg * 2;
    u16* Vt   = (u16*)w;  w += seg * 2;
    u16* CTXs = Xs;   // Xs dead after gemm_qkv_mfma

    convert_split<<<dim3(8192), 256, 0, stream>>>(x, w_qkv, w_proj, Xs, Wqs, Wps);
    gemm_qkv_mfma<<<dim3(768), 256, 0, stream>>>(Xs, Wqs, Qhi, Qlo, Khi, Klo, Vt);
    attn_mfma<<<dim3(1024), 256, 0, stream>>>(Qhi, Qlo, Khi, Klo, Vt, CTXs);
    gemm_proj_mfma<<<dim3(256), 256, 0, stream>>>(CTXs, Wps, b_proj, out);
}

// Round 10
// 233.947 us; speedup vs baseline: 2.7201x; 1.1558x over previous
//
#include <hip/hip_runtime.h>
#include <math.h>

constexpr int EMBED = 1024;
constexpr int HEADS = 16;
constexpr int HDIM  = 64;
constexpr int BATCH = 2;
constexpr int SEQ   = 2048;
constexpr int MTOT  = BATCH * SEQ;   // 4096
constexpr int KSPL  = 3 * EMBED;     // 3072: K' for the 3-term split GEMM
constexpr int LDK   = 2 * EMBED;     // 2048: physical [hi|lo] row width
constexpr int BHSZ  = SEQ * HDIM;    // 131072 elems per (b,h) slice

typedef unsigned short u16;
using bf16x8 = __attribute__((ext_vector_type(8))) short;
using f32x4  = __attribute__((ext_vector_type(4))) float;
using f32x16 = __attribute__((ext_vector_type(16))) float;
using u32x4  = __attribute__((ext_vector_type(4))) unsigned int;

__device__ __forceinline__ u16 f2bf(float f) {
    unsigned u = __builtin_bit_cast(unsigned, f);
    return (u16)((u + 0x7fffu + ((u >> 16) & 1u)) >> 16);
}
__device__ __forceinline__ float bf2f(u16 h) {
    unsigned u = ((unsigned)h) << 16;
    return __builtin_bit_cast(float, u);
}
__device__ __forceinline__ unsigned cvtpk(float lo, float hi) {
    unsigned r;
    asm("v_cvt_pk_bf16_f32 %0, %1, %2" : "=v"(r) : "v"(lo), "v"(hi));
    return r;
}

#define GLOAD16(gp, lp) __builtin_amdgcn_global_load_lds( \
    (const __attribute__((address_space(1))) unsigned int*)(gp), \
    (__attribute__((address_space(3))) unsigned int*)(lp), 16, 0, 0)

// ---------------------------------------------------------------------------
// Split f32 rows into bf16 [hi|lo]; w_qkv rows permuted to [which][h][d].
// ---------------------------------------------------------------------------
__global__ __launch_bounds__(256)
void convert_split(const float* __restrict__ X, const float* __restrict__ Wq,
                   const float* __restrict__ Wp,
                   u16* __restrict__ Xs, u16* __restrict__ Wqs, u16* __restrict__ Wps)
{
    int m = blockIdx.x;                 // 0..8191
    int k = threadIdx.x * 4;
    const float* src; u16* dst;
    if (m < 4096) {
        src = X + (size_t)m * EMBED;          dst = Xs + (size_t)m * LDK;
    } else if (m < 7168) {
        int f = m - 4096;
        int h = f / 192, rem = f - h * 192, d = rem / 3, wq = rem - d * 3;
        int nrow = wq * 1024 + h * 64 + d;
        src = Wq + (size_t)f * EMBED;         dst = Wqs + (size_t)nrow * LDK;
    } else {
        int lm = m - 7168;
        src = Wp + (size_t)lm * EMBED;        dst = Wps + (size_t)lm * LDK;
    }
    float4 v = *(const float4*)(src + k);
    ushort4 hi, lo;
    hi.x = f2bf(v.x); lo.x = f2bf(v.x - bf2f(hi.x));
    hi.y = f2bf(v.y); lo.y = f2bf(v.y - bf2f(hi.y));
    hi.z = f2bf(v.z); lo.z = f2bf(v.z - bf2f(hi.z));
    hi.w = f2bf(v.w); lo.w = f2bf(v.w - bf2f(hi.w));
    *(ushort4*)(dst + k)         = hi;
    *(ushort4*)(dst + EMBED + k) = lo;
}

// ===========================================================================
// QKV GEMM, 256x256 tile, 8 waves (512 thr), BK=64, double-buffered 128KB LDS.
// K'=3072 segment remap: A [hi|lo|hi], B [hi|hi|lo].
// st_16x32-style swizzle: LDS subtiled [rg][cg][16 rows][32 cols], rows 8-15
// of each subtile swap 32B halves. global_load_lds dest is LINEAR; the global
// SOURCE chunk is inverse-swizzled and ds_read applies the same XOR (rule 21).
// Schedule: stage K-tile kt+1 at top of kt (8 loads/thr), 4 phases x 16 MFMA
// (setprio-wrapped), ONE vmcnt(0)+barrier per K-tile (64 MFMA/wave/barrier).
// ===========================================================================
__device__ __forceinline__ void stage8(
    const u16* __restrict__ A, const u16* __restrict__ B,
    u16* SHu, int buf, int kt, int tid)
{
    const int k0 = kt * 64;
    const int ka = k0 < 2048 ? k0 : k0 - 2048;
    const int kb = k0 < 1024 ? k0 : k0 - 1024;
    const int rw  = (tid >> 2) & 15;                      // row within subtile
    const int csw = (tid & 3) ^ (((tid >> 5) & 1) << 1);  // inverse-swizzled 16B chunk
    u16* dst = SHu + buf * 32768;
    #pragma unroll
    for (int i = 0; i < 2; ++i) {
        const int s    = i * 8 + (tid >> 6);              // 0..15: rg*2+cg
        const int row  = (s >> 1) * 16 + rw;              // 0..127 within half
        const int gcol = (s & 1) * 32 + csw * 8;
        const int u8   = (i * 512 + tid) * 8;             // linear LDS elem off
        #pragma unroll
        for (int half = 0; half < 2; ++half) {
            GLOAD16(A + (size_t)(half * 128 + row) * LDK + ka + gcol,
                    dst + half * 8192 + u8);
            GLOAD16(B + (size_t)(half * 128 + row) * LDK + kb + gcol,
                    dst + 16384 + half * 8192 + u8);
        }
    }
}

__global__ __launch_bounds__(512)
void gemm_qkv_8ph(const u16* __restrict__ Xs, const u16* __restrict__ Wqs,
                  u16* __restrict__ Qhi, u16* __restrict__ Qlo,
                  u16* __restrict__ Khi, u16* __restrict__ Klo,
                  u16* __restrict__ Vt)
{
    __shared__ __align__(16) u16 SHu[65536];   // 128 KB: buf0 | buf1 (A|B each)
    const int bid = blockIdx.x;                // 192
    const int xcd = bid & 7, j = bid >> 3;     // j in [0,24)
    const int bm  = xcd * 2 + (j & 1);         // 0..15 (256-row tiles)
    const int bn  = j >> 1;                    // 0..11 (256-col tiles)
    const int tid = threadIdx.x, wid = tid >> 6, lane = tid & 63;
    const int wr  = wid >> 2, wc = wid & 3;    // wave: 128-row x 64-col subtile

    const u16* Ab = Xs  + (size_t)bm * 256 * LDK;
    const u16* Bb = Wqs + (size_t)bn * 256 * LDK;

    const int cwp   = (lane >> 4) ^ (((lane >> 3) & 1) << 1);  // swizzled read chunk
    const int rbase = (lane & 15) * 32 + cwp * 8;
    const int aoff  = wr * 8192 + rbase;                 // + (mi*2+ks)*512
    const int boff  = 16384 + (wc >> 1) * 8192 + rbase;  // + (((wc&1)*4+ni)*2+ks)*512

    f32x4 acc[8][4] = {};

    stage8(Ab, Bb, SHu, 0, 0, tid);
    asm volatile("s_waitcnt vmcnt(0)" ::: "memory");
    __builtin_amdgcn_s_barrier();

    for (int kt = 0; kt < 48; ++kt) {
        const int bufo = (kt & 1) * 32768;
        if (kt + 1 < 48) stage8(Ab, Bb, SHu, (kt + 1) & 1, kt + 1, tid);
        bf16x8 bf[4][2];
        #pragma unroll
        for (int ni = 0; ni < 4; ++ni)
            #pragma unroll
            for (int ks = 0; ks < 2; ++ks)
                bf[ni][ks] = *(const bf16x8*)
                    &SHu[bufo + boff + ((((wc & 1) * 4 + ni) * 2 + ks) * 512)];
        #pragma unroll
        for (int p = 0; p < 4; ++p) {
            bf16x8 af[2][2];
            #pragma unroll
            for (int m2 = 0; m2 < 2; ++m2)
                #pragma unroll
                for (int ks = 0; ks < 2; ++ks)
                    af[m2][ks] = *(const bf16x8*)
                        &SHu[bufo + aoff + (((2 * p + m2) * 2 + ks) * 512)];
            __builtin_amdgcn_s_setprio(1);
            #pragma unroll
            for (int m2 = 0; m2 < 2; ++m2)
                #pragma unroll
                for (int ni = 0; ni < 4; ++ni) {
                    acc[2 * p + m2][ni] = __builtin_amdgcn_mfma_f32_16x16x32_bf16(
                        af[m2][0], bf[ni][0], acc[2 * p + m2][ni], 0, 0, 0);
                    acc[2 * p + m2][ni] = __builtin_amdgcn_mfma_f32_16x16x32_bf16(
                        af[m2][1], bf[ni][1], acc[2 * p + m2][ni], 0, 0, 0);
                }
            __builtin_amdgcn_s_setprio(0);
        }
        asm volatile("s_waitcnt vmcnt(0)" ::: "memory");
        __builtin_amdgcn_s_barrier();
    }

    // ---- epilogue: per wave one (which, head), 2 passes of 64 rows ----
    const int f_base = bn * 256 + wc * 64;
    const int which  = f_base >> 10;
    const int h      = (f_base >> 6) & 15;
    char* T = (char*)(SHu + wid * 8192);       // wave-private 16 KB

    #pragma unroll
    for (int hp = 0; hp < 2; ++hp) {
        const int ng  = bm * 256 + wr * 128 + hp * 64;
        const int b_  = ng >> 11;
        const int n0w = ng & 2047;
        const size_t bhb = (size_t)(b_ * HEADS + h) * BHSZ;

        if (which < 2) {
            u16* dstH = (which == 0 ? Qhi : Khi) + bhb;
            u16* dstL = (which == 0 ? Qlo : Klo) + bhb;
            #pragma unroll
            for (int pass = 0; pass < 2; ++pass) {
                u16* dst = pass ? dstL : dstH;
                #pragma unroll
                for (int mi = 0; mi < 4; ++mi)
                    #pragma unroll
                    for (int ni = 0; ni < 4; ++ni)
                        #pragma unroll
                        for (int r = 0; r < 4; ++r) {
                            float v = acc[hp * 4 + mi][ni][r];
                            u16 hi = f2bf(v);
                            u16 ov = pass ? f2bf(v - bf2f(hi)) : hi;
                            int nl = ((lane >> 4) << 2) + mi * 16 + r;
                            int dl = ni * 16 + (lane & 15);
                            *(u16*)(T + nl * 128 + ((dl * 2) ^ ((nl & 7) << 4))) = ov;
                        }
                #pragma unroll
                for (int t2 = 0; t2 < 2; ++t2)
                    #pragma unroll
                    for (int dt = 0; dt < 4; ++dt) {
                        int nl   = t2 * 32 + (lane & 31);
                        int doff = (dt * 16 + (lane >> 5) * 8) * 2;
                        bf16x8 fr = *(const bf16x8*)(T + nl * 128 + (doff ^ ((nl & 7) << 4)));
                        int tile = (n0w >> 5) + t2;
                        *(bf16x8*)&dst[(size_t)(tile * 4 + dt) * 512 + lane * 8] = fr;
                    }
            }
        } else {
            #pragma unroll
            for (int mi = 0; mi < 4; ++mi)
                #pragma unroll
                for (int ni = 0; ni < 4; ++ni)
                    #pragma unroll
                    for (int r = 0; r < 4; ++r) {
                        int nl = ((lane >> 4) << 2) + mi * 16 + r;
                        int dl = ni * 16 + (lane & 15);
                        *(u16*)(T + nl * 128 + ((dl * 2) ^ ((nl & 7) << 4))) =
                            f2bf(acc[hp * 4 + mi][ni][r]);
                    }
            u16* dst = Vt + bhb;
            #pragma unroll
            for (int t2 = 0; t2 < 2; ++t2)
                #pragma unroll
                for (int dtv = 0; dtv < 2; ++dtv)
                    #pragma unroll
                    for (int kt2 = 0; kt2 < 2; ++kt2) {
                        int dcol = (dtv * 32 + (lane & 31)) * 2;
                        int nb   = t2 * 32 + kt2 * 16 + (lane >> 5) * 8;
                        bf16x8 fr;
                        #pragma unroll
                        for (int j2 = 0; j2 < 8; ++j2) {
                            int nl = nb + j2;
                            fr[j2] = *(const short*)(T + nl * 128 + (dcol ^ ((nl & 7) << 4)));
                        }
                        int tile = (n0w >> 5) + t2;
                        *(bf16x8*)&dst[(size_t)(((tile * 2 + dtv) * 2 + kt2) * 64 + lane) * 8] = fr;
                    }
        }
    }
}

// ---------------------------------------------------------------------------
// Proj GEMM (unchanged R8/R9 structure: 128² depth-2 prefetch + T2 swizzle).
// ---------------------------------------------------------------------------
__device__ __forceinline__ void stage_pf(
    const u16* __restrict__ A, const u16* __restrict__ B,
    u16* As, u16* Bs, int buf, int t, int wid, int lane)
{
    const int k0 = t * 32;
    const int ka = k0 < 2048 ? k0 : k0 - 2048;
    const int kb = k0 < 1024 ? k0 : k0 - 1024;
    const int srow = lane >> 2;
    const int sc   = (((lane & 3) ^ ((lane >> 3) & 3))) * 8;
    u16* ab = As + buf * 4096;
    u16* bb = Bs + buf * 4096;
    #pragma unroll
    for (int i = 0; i < 2; ++i) {
        const int rb = wid * 32 + i * 16;
        GLOAD16(A + (size_t)(rb + srow) * LDK + ka + sc, ab + rb * 32);
        GLOAD16(B + (size_t)(rb + srow) * LDK + kb + sc, bb + rb * 32);
    }
}

__device__ __forceinline__ void mfma_loop_pf(
    const u16* __restrict__ Ab, const u16* __restrict__ Bb,
    u16* As, u16* Bs, f32x4 (&acc)[4][4], int wid, int lane)
{
    constexpr int NT = KSPL / 32;   // 96
    const int wr = wid >> 1, wc = wid & 1;
    const int frow = lane & 15;
    const int kg8s = (((lane >> 4) ^ ((lane >> 1) & 3))) * 8;

    stage_pf(Ab, Bb, As, Bs, 0, 0, wid, lane);
    stage_pf(Ab, Bb, As, Bs, 1, 1, wid, lane);
    asm volatile("s_waitcnt vmcnt(4)" ::: "memory");
    __builtin_amdgcn_s_barrier();
    __builtin_amdgcn_sched_barrier(0);

    int cb = 0, sb = 2;
    for (int t = 0; t < NT; ++t) {
        if (t + 2 < NT) stage_pf(Ab, Bb, As, Bs, sb, t + 2, wid, lane);
        const u16* ap = As + cb * 4096;
        const u16* bp = Bs + cb * 4096;
        bf16x8 a[4], b[4];
        #pragma unroll
        for (int mi = 0; mi < 4; ++mi)
            a[mi] = *(const bf16x8*)&ap[(wr * 64 + mi * 16 + frow) * 32 + kg8s];
        #pragma unroll
        for (int ni = 0; ni < 4; ++ni)
            b[ni] = *(const bf16x8*)&bp[(wc * 64 + ni * 16 + frow) * 32 + kg8s];
        #pragma unroll
        for (int mi = 0; mi < 4; ++mi)
            #pragma unroll
            for (int ni = 0; ni < 4; ++ni)
                acc[mi][ni] = __builtin_amdgcn_mfma_f32_16x16x32_bf16(
                    a[mi], b[ni], acc[mi][ni], 0, 0, 0);
        __builtin_amdgcn_sched_barrier(0);
        asm volatile("s_waitcnt lgkmcnt(0)" ::: "memory");
        if (t + 2 < NT) { asm volatile("s_waitcnt vmcnt(4)" ::: "memory"); }
        else            { asm volatile("s_waitcnt vmcnt(0)" ::: "memory"); }
        __builtin_amdgcn_s_barrier();
        __builtin_amdgcn_sched_barrier(0);
        cb = cb == 2 ? 0 : cb + 1;
        sb = sb == 2 ? 0 : sb + 1;
    }
}

__global__ __launch_bounds__(256)
void gemm_proj_mfma(const u16* __restrict__ CTXs, const u16* __restrict__ Wps,
                    const float* __restrict__ bias, float* __restrict__ Out)
{
    __shared__ __align__(16) u16 SH[6 * 4096];
    const int bid = blockIdx.x;                  // 256
    const int xcd = bid & 7, j = bid >> 3;       // j in [0,32)
    const int bm  = xcd * 4 + (j & 3);           // 0..31
    const int bn  = j >> 2;                      // 0..7
    const int wid = threadIdx.x >> 6, lane = threadIdx.x & 63;
    const int wr = wid >> 1, wc = wid & 1;

    f32x4 acc[4][4] = {};
    mfma_loop_pf(CTXs + (size_t)bm * 128 * LDK, Wps + (size_t)bn * 128 * LDK,
                 SH, SH + 3 * 4096, acc, wid, lane);

    const int m0 = bm * 128 + wr * 64 + ((lane >> 4) << 2);
    #pragma unroll
    for (int ni = 0; ni < 4; ++ni) {
        const int f  = bn * 128 + wc * 64 + ni * 16 + (lane & 15);
        const float bv = bias[f];
        #pragma unroll
        for (int mi = 0; mi < 4; ++mi) {
            const int m = m0 + mi * 16;
            #pragma unroll
            for (int r = 0; r < 4; ++r)
                Out[(size_t)(m + r) * EMBED + f] = fmaxf(acc[mi][ni][r] + bv, 0.f);
        }
    }
}

// ---------------------------------------------------------------------------
// Flash attention (unchanged from R6-R9).
// ---------------------------------------------------------------------------
__global__ __launch_bounds__(256)
void attn_mfma(const u16* __restrict__ Qhi, const u16* __restrict__ Qlo,
               const u16* __restrict__ Khi, const u16* __restrict__ Klo,
               const u16* __restrict__ Vt,  u16* __restrict__ CTXs)
{
    __shared__ __align__(16) float Lot[2][64][33];
    __shared__ float Lml[2][2][32];
    __shared__ __align__(16) float Ol[2][32][68];

    const int bid  = blockIdx.x;                     // 1024
    const int swz  = (bid & 7) * 128 + (bid >> 3);
    const int bh   = swz >> 5;
    const int qp   = swz & 31;
    const int wid  = threadIdx.x >> 6;
    const int lane = threadIdx.x & 63;
    const int col  = lane & 31;
    const int g    = lane >> 5;
    const int qt   = wid >> 1;
    const int kh   = wid & 1;

    const int q0   = qp * 64 + qt * 32;
    const int b_   = bh / HEADS;
    const int h    = bh % HEADS;
    const int tbeg = kh * (SEQ / 2 / 32);
    const int tend = tbeg + SEQ / 2 / 32;

    const size_t bhb = (size_t)bh * BHSZ;
    const u16* kb_hi = Khi + bhb + (size_t)lane * 8;
    const u16* kb_lo = Klo + bhb + (size_t)lane * 8;
    const u16* vb    = Vt  + bhb + (size_t)lane * 8;

    bf16x8 qh[4], ql[4];
    {
        const u16* qbh = Qhi + bhb + (size_t)(q0 >> 5) * 2048 + (size_t)lane * 8;
        const u16* qbl = Qlo + bhb + (size_t)(q0 >> 5) * 2048 + (size_t)lane * 8;
        #pragma unroll
        for (int dt = 0; dt < 4; ++dt) {
            qh[dt] = *(const bf16x8*)(qbh + dt * 512);
            ql[dt] = *(const bf16x8*)(qbl + dt * 512);
        }
    }

    f32x16 ot0 = {}, ot1 = {};
    float m_run = -3.0e38f, l_run = 0.0f;

    bf16x8 kfh[4], kfl[4];
    #pragma unroll
    for (int dt = 0; dt < 4; ++dt) {
        kfh[dt] = *(const bf16x8*)(kb_hi + (size_t)tbeg * 2048 + dt * 512);
        kfl[dt] = *(const bf16x8*)(kb_lo + (size_t)tbeg * 2048 + dt * 512);
    }

    for (int t = tbeg; t < tend; ++t) {
        bf16x8 vf[2][2];
        #pragma unroll
        for (int dt = 0; dt < 2; ++dt)
            #pragma unroll
            for (int kt = 0; kt < 2; ++kt)
                vf[dt][kt] = *(const bf16x8*)(vb + (size_t)t * 2048 + dt * 1024 + kt * 512);

        bf16x8 nkh[4], nkl[4];
        const bool more = (t + 1) < tend;
        if (more) {
            #pragma unroll
            for (int dt = 0; dt < 4; ++dt) {
                nkh[dt] = *(const bf16x8*)(kb_hi + (size_t)(t + 1) * 2048 + dt * 512);
                nkl[dt] = *(const bf16x8*)(kb_lo + (size_t)(t + 1) * 2048 + dt * 512);
            }
        }

        f32x16 st = {};
        #pragma unroll
        for (int dt = 0; dt < 4; ++dt) {
            st = __builtin_amdgcn_mfma_f32_32x32x16_bf16(kfh[dt], qh[dt], st, 0, 0, 0);
            st = __builtin_amdgcn_mfma_f32_32x32x16_bf16(kfh[dt], ql[dt], st, 0, 0, 0);
            st = __builtin_amdgcn_mfma_f32_32x32x16_bf16(kfl[dt], qh[dt], st, 0, 0, 0);
        }

        float mx;
        {
            float m0 = fmaxf(fmaxf(st[0], st[1]),  fmaxf(st[2], st[3]));
            float m1 = fmaxf(fmaxf(st[4], st[5]),  fmaxf(st[6], st[7]));
            float m2 = fmaxf(fmaxf(st[8], st[9]),  fmaxf(st[10], st[11]));
            float m3 = fmaxf(fmaxf(st[12], st[13]), fmaxf(st[14], st[15]));
            mx = fmaxf(fmaxf(m0, m1), fmaxf(m2, m3));
        }
        mx = fmaxf(mx, __shfl_xor(mx, 32));
        if (__ballot(mx > m_run + 8.0f)) {
            float m_new = fmaxf(m_run, mx);
            float corr  = __expf(m_run - m_new);
            l_run *= corr;
            ot0 = ot0 * corr;
            ot1 = ot1 * corr;
            m_run = m_new;
        }

        float p[16];
        #pragma unroll
        for (int r = 0; r < 16; ++r) p[r] = __expf(st[r] - m_run);
        {
            float s0 = (p[0] + p[1]) + (p[2] + p[3]);
            float s1 = (p[4] + p[5]) + (p[6] + p[7]);
            float s2 = (p[8] + p[9]) + (p[10] + p[11]);
            float s3 = (p[12] + p[13]) + (p[14] + p[15]);
            float ps = (s0 + s1) + (s2 + s3);
            ps += __shfl_xor(ps, 32);
            l_run += ps;
        }

        unsigned W0 = cvtpk(p[0],  p[1]),  W1 = cvtpk(p[2],  p[3]);
        unsigned W2 = cvtpk(p[4],  p[5]),  W3 = cvtpk(p[6],  p[7]);
        unsigned W4 = cvtpk(p[8],  p[9]),  W5 = cvtpk(p[10], p[11]);
        unsigned W6 = cvtpk(p[12], p[13]), W7 = cvtpk(p[14], p[15]);
        asm("v_permlane32_swap_b32 %0, %1" : "+v"(W0), "+v"(W2));
        asm("v_permlane32_swap_b32 %0, %1" : "+v"(W1), "+v"(W3));
        asm("v_permlane32_swap_b32 %0, %1" : "+v"(W4), "+v"(W6));
        asm("v_permlane32_swap_b32 %0, %1" : "+v"(W5), "+v"(W7));
        u32x4 t0 = {W0, W1, W2, W3};
        u32x4 t1 = {W4, W5, W6, W7};
        bf16x8 pf0 = __builtin_bit_cast(bf16x8, t0);
        bf16x8 pf1 = __builtin_bit_cast(bf16x8, t1);

        ot0 = __builtin_amdgcn_mfma_f32_32x32x16_bf16(vf[0][0], pf0, ot0, 0, 0, 0);
        ot1 = __builtin_amdgcn_mfma_f32_32x32x16_bf16(vf[1][0], pf0, ot1, 0, 0, 0);
        ot0 = __builtin_amdgcn_mfma_f32_32x32x16_bf16(vf[0][1], pf1, ot0, 0, 0, 0);
        ot1 = __builtin_amdgcn_mfma_f32_32x32x16_bf16(vf[1][1], pf1, ot1, 0, 0, 0);

        if (more) {
            #pragma unroll
            for (int dt = 0; dt < 4; ++dt) { kfh[dt] = nkh[dt]; kfl[dt] = nkl[dt]; }
        }
    }

    if (kh == 1) {
        #pragma unroll
        for (int r = 0; r < 16; ++r) {
            int d = (r & 3) + 8 * (r >> 2) + 4 * g;
            Lot[qt][d][col]      = ot0[r];
            Lot[qt][d + 32][col] = ot1[r];
        }
        if (g == 0) { Lml[qt][0][col] = m_run; Lml[qt][1][col] = l_run; }
    }
    __syncthreads();
    if (kh == 0) {
        float m1 = Lml[qt][0][col], l1 = Lml[qt][1][col];
        float m  = fmaxf(m_run, m1);
        float c0 = __expf(m_run - m), c1 = __expf(m1 - m);
        float l  = l_run * c0 + l1 * c1;
        float sc0 = c0 / (l * 32.0f);
        float sc1 = c1 / (l * 32.0f);
        #pragma unroll
        for (int r = 0; r < 16; ++r) {
            int d = (r & 3) + 8 * (r >> 2) + 4 * g;
            Ol[qt][col][d]      = ot0[r] * sc0 + Lot[qt][d][col] * sc1;
            Ol[qt][col][d + 32] = ot1[r] * sc0 + Lot[qt][d + 32][col] * sc1;
        }
        #pragma unroll
        for (int pass = 0; pass < 8; ++pass) {
            int qq = pass * 4 + (lane >> 4);
            int dd = (lane & 15) * 4;
            float4 t = *(const float4*)&Ol[qt][qq][dd];
            int m_ = b_ * SEQ + q0 + qq;
            ushort4 hv, lv;
            hv.x = f2bf(t.x); lv.x = f2bf(t.x - bf2f(hv.x));
            hv.y = f2bf(t.y); lv.y = f2bf(t.y - bf2f(hv.y));
            hv.z = f2bf(t.z); lv.z = f2bf(t.z - bf2f(hv.z));
            hv.w = f2bf(t.w); lv.w = f2bf(t.w - bf2f(hv.w));
            *(ushort4*)&CTXs[(size_t)m_ * LDK + h * HDIM + dd]         = hv;
            *(ushort4*)&CTXs[(size_t)m_ * LDK + EMBED + h * HDIM + dd] = lv;
        }
    }
}

extern "C" void kernel_launch(void* const* d_in, const int* in_sizes, int n_in,
                              void* d_out, int out_size, void* d_ws, size_t ws_size,
                              hipStream_t stream)
{
    const float* x      = (const float*)d_in[0];
    const float* w_qkv  = (const float*)d_in[1];
    const float* w_proj = (const float*)d_in[2];
    const float* b_proj = (const float*)d_in[3];
    float* out = (float*)d_out;

    const size_t seg = (size_t)BATCH * HEADS * SEQ * HDIM;   // 4 Mi elems
    char* w = (char*)d_ws;
    u16* Xs   = (u16*)w;  w += (size_t)MTOT * LDK * 2;       // 16 MiB
    u16* Wqs  = (u16*)w;  w += (size_t)3 * EMBED * LDK * 2;  // 12 MiB
    u16* Wps  = (u16*)w;  w += (size_t)EMBED * LDK * 2;      // 4 MiB
    u16* Qhi  = (u16*)w;  w += seg * 2;
    u16* Qlo  = (u16*)w;  w += seg * 2;
    u16* Khi  = (u16*)w;  w += seg * 2;
    u16* Klo  = (u16*)w;  w += seg * 2;
    u16* Vt   = (u16*)w;  w += seg * 2;
    u16* CTXs = Xs;   // Xs dead after gemm_qkv_8ph

    convert_split<<<dim3(8192), 256, 0, stream>>>(x, w_qkv, w_proj, Xs, Wqs, Wps);
    gemm_qkv_8ph<<<dim3(192), 512, 0, stream>>>(Xs, Wqs, Qhi, Qlo, Khi, Klo, Vt);
    attn_mfma<<<dim3(1024), 256, 0, stream>>>(Qhi, Qlo, Khi, Klo, Vt, CTXs);
    gemm_proj_mfma<<<dim3(256), 256, 0, stream>>>(CTXs, Wps, b_proj, out);
}